// Round 15
// baseline (234.292 us; speedup 1.0000x reference)
//
#include <hip/hip_runtime.h>

// ---------------------------------------------------------------------------
// PatchFeatureExtractor: EdgeConv block — R14.
//   R13b analysis: ballot swap was issue-count-neutral (bank conflicts -> 0,
//   VALUBusy 61->66%, dur flat) — knn is VALU-issue + L2-traffic bound.
//   R14: 8 queries/wave (32/block, grid 512): halves candidate L2 re-reads
//   and per-iter overhead per query; 8 independent eval chains of ILP per
//   wave fill the ~34% stall. LDS 32KB/block (grid-limited 2 blocks/CU).
//   Ordering formula untouched (R13's lesson: f32 ordering must remain
//   bit-identical to the empirically-matched form).
//   Frozen: R12 main/stats2 pipelines, mom, affine1, parallel affine2, out.
// ---------------------------------------------------------------------------

typedef __attribute__((ext_vector_type(8)))  short short8;
typedef __attribute__((ext_vector_type(4)))  float floatx4;

#define BATCH 4
#define NPTS  4096
#define KNN   20
#define BN_   (BATCH*NPTS)          // 16384 points
#define CNT   (BATCH*NPTS*KNN)      // 327680 positions

__device__ __forceinline__ unsigned short f2bf(float f) {
  unsigned u = __float_as_uint(f);
  unsigned r = u + 0x7FFFu + ((u >> 16) & 1u);   // RNE
  return (unsigned short)(r >> 16);
}

__device__ __forceinline__ unsigned cvtpk(float lo, float hi) {
  unsigned r;
  asm("v_cvt_pk_bf16_f32 %0, %1, %2" : "=v"(r) : "v"(lo), "v"(hi));
  return r;
}

union PK8 { unsigned u4[4]; short8 s; };

__device__ __forceinline__ void store4bf_relu(unsigned short* dst, floatx4 v) {
  unsigned lo = cvtpk(fmaxf(v[0],0.f), fmaxf(v[1],0.f));
  unsigned hi = cvtpk(fmaxf(v[2],0.f), fmaxf(v[3],0.f));
  *(uint2*)dst = make_uint2(lo, hi);
}

__device__ __forceinline__ unsigned mono(float f) {
  unsigned u = __float_as_uint(f);
  return u ^ ((unsigned)((int)u >> 31) | 0x80000000u);
}

__device__ __forceinline__ int mbcnt64(unsigned long long m) {
  return __builtin_amdgcn_mbcnt_hi((unsigned)(m >> 32),
         __builtin_amdgcn_mbcnt_lo((unsigned)m, 0));
}

// BN affine from RAW (bias-free) sums: conv bias cancels in train-mode BN
__device__ __forceinline__ void bn_affine(float gsum, float gsq, float gamma,
                                          float beta, float& s, float& sh) {
  const float inv = 1.0f / (float)CNT;
  float mean = gsum * inv;
  float var  = gsq * inv - mean * mean;
  s  = gamma * rsqrtf(var + 1e-5f);
  sh = beta - mean * s;
}

// ------------------------------- K0 prep -----------------------------------
__global__ void pf_prep(const float* __restrict__ x, float4* __restrict__ xp,
                        float* __restrict__ stats,
                        const float* __restrict__ W2, const float* __restrict__ W3,
                        unsigned short* __restrict__ w2p,
                        unsigned short* __restrict__ w3p) {
  int pt = blockIdx.x * 256 + threadIdx.x;      // grid 64 x 256 = 16384
  float x0 = x[pt*3+0], x1 = x[pt*3+1], x2 = x[pt*3+2];
  float xx = x0*x0 + x1*x1 + x2*x2;             // |x|^2 (proven ordering)
  xp[pt] = make_float4(x0, x1, x2, xx);
  if (blockIdx.x == 0)
    for (int i = threadIdx.x; i < 640; i += 256) stats[i] = 0.0f;
  if (blockIdx.x == 1) {
    for (int i = threadIdx.x; i < 128*64;  i += 256) w2p[i] = f2bf(W2[i]);
    for (int i = threadIdx.x; i < 128*128; i += 256) w3p[i] = f2bf(W3[i]);
  }
}

// ------------------------------- K1 knn ------------------------------------
__device__ __forceinline__ float sort_take20th(float v, int lane) {
  #pragma unroll
  for (int k = 2; k <= 64; k <<= 1) {
    #pragma unroll
    for (int j = k >> 1; j >= 1; j >>= 1) {
      float o = __shfl_xor(v, j);
      bool keepmax = (((lane & j) == 0) == ((lane & k) == 0));
      v = keepmax ? fmaxf(v, o) : fminf(v, o);
    }
  }
  return __shfl(v, 19);
}

__device__ __forceinline__ unsigned long long sort64_desc(unsigned long long v,
                                                          int lane) {
  #pragma unroll
  for (int k = 2; k <= 64; k <<= 1) {
    #pragma unroll
    for (int j = k >> 1; j >= 1; j >>= 1) {
      unsigned long long o = __shfl_xor(v, j);
      bool keepmax = (((lane & j) == 0) == ((lane & k) == 0));
      unsigned long long hi = v > o ? v : o;
      unsigned long long lo = v > o ? o : v;
      v = keepmax ? hi : lo;
    }
  }
  return v;
}

// grid 512: 32 queries/block, 8 per wave; no barriers (per-wave lists).
__global__ __launch_bounds__(256) void pf_knn(const float4* __restrict__ xp,
                                              int* __restrict__ idxb) {
  __shared__ unsigned long long lst[32][128];   // 32 KB, per-wave-private
  const int tid  = threadIdx.x;
  const int lane = tid & 63;
  const int w    = tid >> 6;
  const int b    = blockIdx.x >> 7;                    // 128 blocks/batch
  const int nb   = (blockIdx.x & 127) * 32 + w * 8;    // 8 queries per wave
  const float4* xb = xp + b * NPTS;

  float4 q0 = xb[nb+0], q1 = xb[nb+1], q2 = xb[nb+2], q3 = xb[nb+3];
  float4 q4 = xb[nb+4], q5 = xb[nb+5], q6 = xb[nb+6], q7 = xb[nb+7];

  // pass 1: per-lane max pd over its 64-candidate strip (proven formula)
  float mx0=-3.0e38f, mx1=-3.0e38f, mx2=-3.0e38f, mx3=-3.0e38f;
  float mx4=-3.0e38f, mx5=-3.0e38f, mx6=-3.0e38f, mx7=-3.0e38f;
  for (int j0 = 0; j0 < NPTS; j0 += 64) {
    float4 c = xb[j0 + lane];
    float d0 = fmaf(q0.x,c.x, fmaf(q0.y,c.y, q0.z*c.z));
    float d1 = fmaf(q1.x,c.x, fmaf(q1.y,c.y, q1.z*c.z));
    float d2 = fmaf(q2.x,c.x, fmaf(q2.y,c.y, q2.z*c.z));
    float d3 = fmaf(q3.x,c.x, fmaf(q3.y,c.y, q3.z*c.z));
    float d4 = fmaf(q4.x,c.x, fmaf(q4.y,c.y, q4.z*c.z));
    float d5 = fmaf(q5.x,c.x, fmaf(q5.y,c.y, q5.z*c.z));
    float d6 = fmaf(q6.x,c.x, fmaf(q6.y,c.y, q6.z*c.z));
    float d7 = fmaf(q7.x,c.x, fmaf(q7.y,c.y, q7.z*c.z));
    mx0 = fmaxf(mx0, fmaf(2.f,d0,-q0.w) - c.w);
    mx1 = fmaxf(mx1, fmaf(2.f,d1,-q1.w) - c.w);
    mx2 = fmaxf(mx2, fmaf(2.f,d2,-q2.w) - c.w);
    mx3 = fmaxf(mx3, fmaf(2.f,d3,-q3.w) - c.w);
    mx4 = fmaxf(mx4, fmaf(2.f,d4,-q4.w) - c.w);
    mx5 = fmaxf(mx5, fmaf(2.f,d5,-q5.w) - c.w);
    mx6 = fmaxf(mx6, fmaf(2.f,d6,-q6.w) - c.w);
    mx7 = fmaxf(mx7, fmaf(2.f,d7,-q7.w) - c.w);
  }
  // T = 20th largest of the 64 lane-maxes: provably <= true 20th-largest pd
  float T0 = sort_take20th(mx0, lane);
  float T1 = sort_take20th(mx1, lane);
  float T2 = sort_take20th(mx2, lane);
  float T3 = sort_take20th(mx3, lane);
  float T4 = sort_take20th(mx4, lane);
  float T5 = sort_take20th(mx5, lane);
  float T6 = sort_take20th(mx6, lane);
  float T7 = sort_take20th(mx7, lane);

  // pass 2: ballot compaction (order carried in the 64-bit key)
  int cur0=0, cur1=0, cur2=0, cur3=0, cur4=0, cur5=0, cur6=0, cur7=0;
  for (int j0 = 0; j0 < NPTS; j0 += 64) {
    float4 c = xb[j0 + lane];
    unsigned long long kb = (unsigned long long)(4095 - (j0 + lane));
    unsigned long long lm = (1ull << lane) - 1ull;
    {
      float d = fmaf(q0.x,c.x, fmaf(q0.y,c.y, q0.z*c.z));
      float p = fmaf(2.f,d,-q0.w) - c.w;
      bool h = p >= T0; unsigned long long m = __ballot(h);
      if (h) { int o = cur0 + mbcnt64(m & lm);
               if (o < 128) lst[w*8+0][o] = ((unsigned long long)mono(p) << 32) | kb; }
      cur0 += __popcll(m);
    }
    {
      float d = fmaf(q1.x,c.x, fmaf(q1.y,c.y, q1.z*c.z));
      float p = fmaf(2.f,d,-q1.w) - c.w;
      bool h = p >= T1; unsigned long long m = __ballot(h);
      if (h) { int o = cur1 + mbcnt64(m & lm);
               if (o < 128) lst[w*8+1][o] = ((unsigned long long)mono(p) << 32) | kb; }
      cur1 += __popcll(m);
    }
    {
      float d = fmaf(q2.x,c.x, fmaf(q2.y,c.y, q2.z*c.z));
      float p = fmaf(2.f,d,-q2.w) - c.w;
      bool h = p >= T2; unsigned long long m = __ballot(h);
      if (h) { int o = cur2 + mbcnt64(m & lm);
               if (o < 128) lst[w*8+2][o] = ((unsigned long long)mono(p) << 32) | kb; }
      cur2 += __popcll(m);
    }
    {
      float d = fmaf(q3.x,c.x, fmaf(q3.y,c.y, q3.z*c.z));
      float p = fmaf(2.f,d,-q3.w) - c.w;
      bool h = p >= T3; unsigned long long m = __ballot(h);
      if (h) { int o = cur3 + mbcnt64(m & lm);
               if (o < 128) lst[w*8+3][o] = ((unsigned long long)mono(p) << 32) | kb; }
      cur3 += __popcll(m);
    }
    {
      float d = fmaf(q4.x,c.x, fmaf(q4.y,c.y, q4.z*c.z));
      float p = fmaf(2.f,d,-q4.w) - c.w;
      bool h = p >= T4; unsigned long long m = __ballot(h);
      if (h) { int o = cur4 + mbcnt64(m & lm);
               if (o < 128) lst[w*8+4][o] = ((unsigned long long)mono(p) << 32) | kb; }
      cur4 += __popcll(m);
    }
    {
      float d = fmaf(q5.x,c.x, fmaf(q5.y,c.y, q5.z*c.z));
      float p = fmaf(2.f,d,-q5.w) - c.w;
      bool h = p >= T5; unsigned long long m = __ballot(h);
      if (h) { int o = cur5 + mbcnt64(m & lm);
               if (o < 128) lst[w*8+5][o] = ((unsigned long long)mono(p) << 32) | kb; }
      cur5 += __popcll(m);
    }
    {
      float d = fmaf(q6.x,c.x, fmaf(q6.y,c.y, q6.z*c.z));
      float p = fmaf(2.f,d,-q6.w) - c.w;
      bool h = p >= T6; unsigned long long m = __ballot(h);
      if (h) { int o = cur6 + mbcnt64(m & lm);
               if (o < 128) lst[w*8+6][o] = ((unsigned long long)mono(p) << 32) | kb; }
      cur6 += __popcll(m);
    }
    {
      float d = fmaf(q7.x,c.x, fmaf(q7.y,c.y, q7.z*c.z));
      float p = fmaf(2.f,d,-q7.w) - c.w;
      bool h = p >= T7; unsigned long long m = __ballot(h);
      if (h) { int o = cur7 + mbcnt64(m & lm);
               if (o < 128) lst[w*8+7][o] = ((unsigned long long)mono(p) << 32) | kb; }
      cur7 += __popcll(m);
    }
  }

  // exact top-20 per query
  #pragma unroll 1
  for (int i = 0; i < 8; ++i) {
    const int li = w*8 + i;
    const int cn = (i==0)?cur0:(i==1)?cur1:(i==2)?cur2:(i==3)?cur3:
                   (i==4)?cur4:(i==5)?cur5:(i==6)?cur6:cur7;
    const int outbase = (b * NPTS + nb + i) * KNN;
    if (cn <= 64) {                       // common case: one sort
      unsigned long long v = (lane < cn) ? lst[li][lane] : 0ull;
      v = sort64_desc(v, lane);
      if (lane < KNN) idxb[outbase + lane] = 4095 - (int)(v & 0xFFFFFFFFull);
    } else if (cn <= 128) {               // rare: 20-round argmax on 2 regs
      unsigned long long e0 = lst[li][lane];
      unsigned long long e1 = (lane + 64 < cn) ? lst[li][lane + 64] : 0ull;
      #pragma unroll 1
      for (int r = 0; r < KNN; ++r) {
        unsigned long long m = e0 > e1 ? e0 : e1;
        #pragma unroll
        for (int o = 32; o; o >>= 1) {
          unsigned long long t = __shfl_xor(m, o);
          m = t > m ? t : m;
        }
        if (lane == 0) idxb[outbase + r] = 4095 - (int)(m & 0xFFFFFFFFull);
        if (e0 == m) e0 = 0ull; else if (e1 == m) e1 = 0ull;
      }
    } else {                              // ~never: exact full re-scan
      const float4 qq = (i==0)?q0:(i==1)?q1:(i==2)?q2:(i==3)?q3:
                        (i==4)?q4:(i==5)?q5:(i==6)?q6:q7;
      unsigned long long prev = ~0ull;
      #pragma unroll 1
      for (int r = 0; r < KNN; ++r) {
        unsigned long long best = 0ull;
        for (int j0 = 0; j0 < NPTS; j0 += 64) {
          float4 c = xb[j0 + lane];
          float dd = fmaf(qq.x,c.x, fmaf(qq.y,c.y, qq.z*c.z));
          float pd = fmaf(2.f,dd,-qq.w) - c.w;
          unsigned long long key = ((unsigned long long)mono(pd) << 32) |
                                   (unsigned long long)(4095 - (j0 + lane));
          if (key < prev && key > best) best = key;
        }
        #pragma unroll
        for (int o = 32; o; o >>= 1) {
          unsigned long long t = __shfl_xor(best, o);
          best = t > best ? t : best;
        }
        if (lane == 0) idxb[outbase + r] = 4095 - (int)(best & 0xFFFFFFFFull);
        prev = best;
      }
    }
  }
}

// ------------------------------- K2 moments --------------------------------
__global__ __launch_bounds__(256) void pf_mom(
    const float4* __restrict__ xp, const int* __restrict__ idxb,
    float* __restrict__ gm) {
  __shared__ float WM[4][27];
  const int tid = threadIdx.x, lane = tid & 63, w = tid >> 6;
  const int pt = blockIdx.x * 256 + tid;
  const float4 xi = xp[pt];
  const int ib = (pt >> 12) << 12;

  int idx[KNN];
  const int4* ip = (const int4*)(idxb + pt*KNN);
  #pragma unroll
  for (int q = 0; q < 5; ++q) {
    int4 v = ip[q];
    idx[q*4+0]=v.x; idx[q*4+1]=v.y; idx[q*4+2]=v.z; idx[q*4+3]=v.w;
  }
  float sj0=0,sj1=0,sj2=0, p0=0,p1=0,p2=0,p3=0,p4=0,p5=0;
  #pragma unroll
  for (int kk = 0; kk < KNN; ++kk) {
    float4 xj = xp[ib + idx[kk]];
    sj0 += xj.x; sj1 += xj.y; sj2 += xj.z;
    p0 = fmaf(xj.x,xj.x,p0); p1 = fmaf(xj.x,xj.y,p1); p2 = fmaf(xj.x,xj.z,p2);
    p3 = fmaf(xj.y,xj.y,p3); p4 = fmaf(xj.y,xj.z,p4); p5 = fmaf(xj.z,xj.z,p5);
  }
  float m[27];
  m[0]=sj0; m[1]=sj1; m[2]=sj2;
  m[3]=20.f*xi.x; m[4]=20.f*xi.y; m[5]=20.f*xi.z;
  m[6]=p0; m[7]=p1; m[8]=p2; m[9]=p3; m[10]=p4; m[11]=p5;
  m[12]=20.f*xi.x*xi.x; m[13]=20.f*xi.x*xi.y; m[14]=20.f*xi.x*xi.z;
  m[15]=20.f*xi.y*xi.y; m[16]=20.f*xi.y*xi.z; m[17]=20.f*xi.z*xi.z;
  m[18]=sj0*xi.x; m[19]=sj0*xi.y; m[20]=sj0*xi.z;
  m[21]=sj1*xi.x; m[22]=sj1*xi.y; m[23]=sj1*xi.z;
  m[24]=sj2*xi.x; m[25]=sj2*xi.y; m[26]=sj2*xi.z;
  #pragma unroll
  for (int c = 0; c < 27; ++c) {
    float v = m[c];
    #pragma unroll
    for (int o = 32; o; o >>= 1) v += __shfl_xor(v, o);
    m[c] = v;
  }
  if (lane == 0)
    #pragma unroll
    for (int c = 0; c < 27; ++c) WM[w][c] = m[c];
  __syncthreads();
  if (tid < 27) atomicAdd(&gm[tid], WM[0][tid]+WM[1][tid]+WM[2][tid]+WM[3][tid]);
}

// ------------------------------- K3 affine1 --------------------------------
__global__ void pf_affine1(const float* __restrict__ gm,
                           const float* __restrict__ W1,
                           const float* __restrict__ g1,
                           const float* __restrict__ be1,
                           unsigned short* __restrict__ w1s,
                           float* __restrict__ sh1e) {
  int c = threadIdx.x;
  if (c >= 64) return;
  const float* wr = W1 + c*6;
  const float wa[3] = {wr[0], wr[1], wr[2]};
  const float wb[3] = {wr[3], wr[4], wr[5]};
  const int si0[9] = {0,1,2, 1,3,4, 2,4,5};
  float syf = 0.f, sy2 = 0.f;
  #pragma unroll
  for (int a = 0; a < 3; ++a)
    syf += wa[a]*(gm[a] - gm[3+a]) + wb[a]*gm[3+a];
  #pragma unroll
  for (int a = 0; a < 3; ++a)
    #pragma unroll
    for (int bq = 0; bq < 3; ++bq) {
      int k = a*3 + bq, kt = bq*3 + a;
      float pjj = gm[6 + si0[k]], pii = gm[12 + si0[k]];
      float cc = gm[18 + k], ct = gm[18 + kt];
      float uu = pjj - cc - ct + pii;
      float uv = cc - pii;
      sy2 += wa[a]*wa[bq]*uu + 2.f*wa[a]*wb[bq]*uv + wb[a]*wb[bq]*pii;
    }
  const float inv = 1.0f / (float)CNT;
  float mean = syf * inv;
  float var  = sy2 * inv - mean * mean;
  float s  = g1[c] * rsqrtf(var + 1e-5f);
  sh1e[c]  = be1[c] - mean * s;
  unsigned short* o = w1s + c*8;
  o[0]=f2bf(s*wa[0]); o[1]=f2bf(s*wa[1]); o[2]=f2bf(s*wa[2]);
  o[3]=f2bf(s*wb[0]); o[4]=f2bf(s*wb[1]); o[5]=f2bf(s*wb[2]);
  o[6]=0; o[7]=0;
}

// ------------------------------- K5 affine2 --------------------------------
// grid 32 x 256 = 8192 threads, one W2 element each (redundant bn_affine).
__global__ void pf_affine2(const float* __restrict__ gs2,
                           const float* __restrict__ gq2,
                           const float* __restrict__ W2,
                           const float* __restrict__ g2,
                           const float* __restrict__ be2,
                           unsigned short* __restrict__ w2s,
                           float* __restrict__ shm2) {
  int g = blockIdx.x * 256 + threadIdx.x;
  if (g >= 128*64) return;
  int c = g >> 6, j = g & 63;
  float s, sh; bn_affine(gs2[c], gq2[c], g2[c], be2[c], s, sh);
  if (j == 0) shm2[c] = sh;
  w2s[g] = f2bf(s * W2[g]);
}

// ------------------------------- K4 stats2 ---------------------------------
// grid 512, 32 pts/block (two point-halves), 2-stage pipeline, 1 barrier/iter.
__global__ __launch_bounds__(256, 3) void pf_stats2(
    const float4* __restrict__ xp, const int* __restrict__ idxb,
    const unsigned short* __restrict__ w1s, const float* __restrict__ sh1e,
    const unsigned short* __restrict__ w2p,
    float* __restrict__ gs2, float* __restrict__ gq2) {
  __shared__ __align__(16) short8 AF[KNN][32];             // 10 KB
  __shared__ __align__(16) unsigned short H1[2][32][72];   // 9 KB
  __shared__ float SS[128], SQ[128];

  const int tid = threadIdx.x;
  const int lane = tid & 63, ww = tid >> 6;
  const int l15 = lane & 15, quad = lane >> 4;
  const int pt0 = blockIdx.x * 32;

  if (tid < 128) { SS[tid] = 0.f; SQ[tid] = 0.f; }

  for (int u = tid; u < 32*KNN; u += 256) {
    int kk = u >> 5, pp = u & 31;
    int pt = pt0 + pp;
    float4 xi = xp[pt];
    float4 xj = xp[((pt >> 12) << 12) + idxb[pt*KNN + kk]];
    PK8 U;
    U.u4[0] = cvtpk(xj.x-xi.x, xj.y-xi.y);
    U.u4[1] = cvtpk(xj.z-xi.z, xi.x);
    U.u4[2] = cvtpk(xi.y, xi.z);
    U.u4[3] = 0;
    AF[kk][pp] = U.s;
  }

  short8 w1f = *(const short8*)(w1s + (16*ww + l15)*8);
  floatx4 sh1v;
  #pragma unroll
  for (int r = 0; r < 4; ++r) sh1v[r] = sh1e[16*ww + 4*quad + r];

  short8 w2f[2][2];
  #pragma unroll
  for (int ks = 0; ks < 2; ++ks)
    #pragma unroll
    for (int t = 0; t < 2; ++t)
      w2f[ks][t] = *(const short8*)(w2p + (32*ww + 16*t + l15)*64 + 32*ks + quad*8);

  float sum[2][2][4] = {{{0,0,0,0},{0,0,0,0}},{{0,0,0,0},{0,0,0,0}}};
  float sq [2][2][4] = {{{0,0,0,0},{0,0,0,0}},{{0,0,0,0},{0,0,0,0}}};
  const short8 z8 = {0,0,0,0,0,0,0,0};
  __syncthreads();

  #pragma unroll 1
  for (int k = 0; k < KNN + 1; ++k) {
    // stage 2: L2(k-1) for both point-halves
    if (k >= 1) {
      #pragma unroll
      for (int ph = 0; ph < 2; ++ph) {
        floatx4 acc2[2] = {{0,0,0,0},{0,0,0,0}};
        #pragma unroll
        for (int ks = 0; ks < 2; ++ks) {
          short8 a = *(const short8*)&H1[(k-1) & 1][ph*16 + l15][ks*32 + quad*8];
          #pragma unroll
          for (int t = 0; t < 2; ++t)
            acc2[t] = __builtin_amdgcn_mfma_f32_16x16x32_bf16(w2f[ks][t], a, acc2[t], 0,0,0);
        }
        #pragma unroll
        for (int t = 0; t < 2; ++t)
          #pragma unroll
          for (int r = 0; r < 4; ++r) {
            float v = acc2[t][r];          // raw conv2 (bias cancels in BN)
            sum[ph][t][r] += v; sq[ph][t][r] = fmaf(v, v, sq[ph][t][r]);
          }
      }
    }
    // stage 1: L1(k) for both point-halves -> H1[k&1]
    if (k < KNN) {
      #pragma unroll
      for (int ph = 0; ph < 2; ++ph) {
        short8 a0 = z8;
        if (quad == 0) a0 = AF[k][ph*16 + l15];
        floatx4 c0 = sh1v;
        c0 = __builtin_amdgcn_mfma_f32_16x16x32_bf16(w1f, a0, c0, 0,0,0);
        store4bf_relu(&H1[k & 1][ph*16 + l15][16*ww + 4*quad], c0);
      }
    }
    __syncthreads();                       // single barrier per iteration
  }
  #pragma unroll
  for (int t = 0; t < 2; ++t)
    #pragma unroll
    for (int r = 0; r < 4; ++r) {
      float s = sum[0][t][r] + sum[1][t][r];
      float z = sq[0][t][r] + sq[1][t][r];
      s += __shfl_xor(s, 1); z += __shfl_xor(z, 1);
      s += __shfl_xor(s, 2); z += __shfl_xor(z, 2);
      s += __shfl_xor(s, 4); z += __shfl_xor(z, 4);
      s += __shfl_xor(s, 8); z += __shfl_xor(z, 8);
      if (l15 == 0) {
        int ch = 32*ww + 16*t + 4*quad + r;
        atomicAdd(&SS[ch], s); atomicAdd(&SQ[ch], z);
      }
    }
  __syncthreads();
  if (tid < 128) { atomicAdd(&gs2[tid], SS[tid]); atomicAdd(&gq2[tid], SQ[tid]); }
}

// ------------------------------- K6 main -----------------------------------
// grid 512, 32 pts/block (two point-halves), 3-stage pipeline, 1 barrier/iter.
__global__ __launch_bounds__(256, 2) void pf_main(
    const float4* __restrict__ xp, const int* __restrict__ idxb,
    const unsigned short* __restrict__ w1s, const float* __restrict__ sh1e,
    const unsigned short* __restrict__ w2s, const float* __restrict__ shm2,
    const unsigned short* __restrict__ w3p,
    float* __restrict__ gs3, float* __restrict__ gq3,
    float* __restrict__ maxv) {
  __shared__ __align__(16) short8 AF[KNN][32];             // 10 KB
  __shared__ __align__(16) unsigned short H1[2][32][72];   // 9 KB
  __shared__ __align__(16) unsigned short H2[2][32][136];  // 17 KB
  __shared__ float SS[128], SQ[128];

  const int tid = threadIdx.x;
  const int lane = tid & 63, ww = tid >> 6;
  const int l15 = lane & 15, quad = lane >> 4;
  const int pt0 = blockIdx.x * 32;

  if (tid < 128) { SS[tid] = 0.f; SQ[tid] = 0.f; }

  for (int u = tid; u < 32*KNN; u += 256) {
    int kk = u >> 5, pp = u & 31;
    int pt = pt0 + pp;
    float4 xi = xp[pt];
    float4 xj = xp[((pt >> 12) << 12) + idxb[pt*KNN + kk]];
    PK8 U;
    U.u4[0] = cvtpk(xj.x-xi.x, xj.y-xi.y);
    U.u4[1] = cvtpk(xj.z-xi.z, xi.x);
    U.u4[2] = cvtpk(xi.y, xi.z);
    U.u4[3] = 0;
    AF[kk][pp] = U.s;
  }

  short8 w1f = *(const short8*)(w1s + (16*ww + l15)*8);
  floatx4 sh1v;
  #pragma unroll
  for (int r = 0; r < 4; ++r) sh1v[r] = sh1e[16*ww + 4*quad + r];
  short8 w2f[2][2];
  #pragma unroll
  for (int ks = 0; ks < 2; ++ks)
    #pragma unroll
    for (int t = 0; t < 2; ++t)
      w2f[ks][t] = *(const short8*)(w2s + (32*ww + 16*t + l15)*64 + 32*ks + quad*8);
  floatx4 sh2v[2];
  #pragma unroll
  for (int t = 0; t < 2; ++t)
    #pragma unroll
    for (int r = 0; r < 4; ++r)
      sh2v[t][r] = shm2[32*ww + 16*t + 4*quad + r];
  short8 w3f[4][2];
  #pragma unroll
  for (int ks = 0; ks < 4; ++ks)
    #pragma unroll
    for (int t = 0; t < 2; ++t)
      w3f[ks][t] = *(const short8*)(w3p + (32*ww + 16*t + l15)*128 + 32*ks + quad*8);

  float sum[2][2][4] = {{{0,0,0,0},{0,0,0,0}},{{0,0,0,0},{0,0,0,0}}};
  float sq [2][2][4] = {{{0,0,0,0},{0,0,0,0}},{{0,0,0,0},{0,0,0,0}}};
  float mx [2][2][4];
  #pragma unroll
  for (int ph = 0; ph < 2; ++ph)
    #pragma unroll
    for (int t = 0; t < 2; ++t)
      #pragma unroll
      for (int r = 0; r < 4; ++r) mx[ph][t][r] = -3.0e38f;

  const short8 z8 = {0,0,0,0,0,0,0,0};
  __syncthreads();

  #pragma unroll 1
  for (int k = 0; k < KNN + 2; ++k) {
    // ---- stage 3: L3(k-2) from H2[(k-2)&1] == H2[k&1] ----
    if (k >= 2) {
      #pragma unroll
      for (int ph = 0; ph < 2; ++ph) {
        floatx4 acc3[2] = {{0,0,0,0},{0,0,0,0}};
        #pragma unroll
        for (int ks = 0; ks < 4; ++ks) {
          short8 a = *(const short8*)&H2[k & 1][ph*16 + l15][ks*32 + quad*8];
          #pragma unroll
          for (int t = 0; t < 2; ++t)
            acc3[t] = __builtin_amdgcn_mfma_f32_16x16x32_bf16(w3f[ks][t], a, acc3[t], 0,0,0);
        }
        #pragma unroll
        for (int t = 0; t < 2; ++t)
          #pragma unroll
          for (int r = 0; r < 4; ++r) {
            float v = acc3[t][r];
            sum[ph][t][r] += v; sq[ph][t][r] = fmaf(v, v, sq[ph][t][r]);
            mx[ph][t][r] = fmaxf(mx[ph][t][r], v);
          }
      }
    }
    // ---- stage 2: L2(k-1) from H1[(k-1)&1] -> H2[(k-1)&1] ----
    if (k >= 1 && k < KNN + 1) {
      #pragma unroll
      for (int ph = 0; ph < 2; ++ph) {
        floatx4 acc2[2] = {sh2v[0], sh2v[1]};
        #pragma unroll
        for (int ks = 0; ks < 2; ++ks) {
          short8 a = *(const short8*)&H1[(k-1) & 1][ph*16 + l15][ks*32 + quad*8];
          #pragma unroll
          for (int t = 0; t < 2; ++t)
            acc2[t] = __builtin_amdgcn_mfma_f32_16x16x32_bf16(w2f[ks][t], a, acc2[t], 0,0,0);
        }
        #pragma unroll
        for (int t = 0; t < 2; ++t)
          store4bf_relu(&H2[(k-1) & 1][ph*16 + l15][32*ww + 16*t + 4*quad], acc2[t]);
      }
    }
    // ---- stage 1: L1(k) -> H1[k&1] ----
    if (k < KNN) {
      #pragma unroll
      for (int ph = 0; ph < 2; ++ph) {
        short8 a0 = z8;
        if (quad == 0) a0 = AF[k][ph*16 + l15];
        floatx4 acc1 = sh1v;
        acc1 = __builtin_amdgcn_mfma_f32_16x16x32_bf16(w1f, a0, acc1, 0,0,0);
        store4bf_relu(&H1[k & 1][ph*16 + l15][16*ww + 4*quad], acc1);
      }
    }
    __syncthreads();                       // single barrier per iteration
  }

  #pragma unroll
  for (int ph = 0; ph < 2; ++ph)
    #pragma unroll
    for (int t = 0; t < 2; ++t) {
      int ch0 = 32*ww + 16*t + 4*quad;
      float4 o = make_float4(mx[ph][t][0], mx[ph][t][1], mx[ph][t][2], mx[ph][t][3]);
      *(float4*)&maxv[(size_t)(pt0 + ph*16 + l15)*128 + ch0] = o;
    }
  #pragma unroll
  for (int t = 0; t < 2; ++t)
    #pragma unroll
    for (int r = 0; r < 4; ++r) {
      float s = sum[0][t][r] + sum[1][t][r];
      float z = sq[0][t][r] + sq[1][t][r];
      s += __shfl_xor(s, 1); z += __shfl_xor(z, 1);
      s += __shfl_xor(s, 2); z += __shfl_xor(z, 2);
      s += __shfl_xor(s, 4); z += __shfl_xor(z, 4);
      s += __shfl_xor(s, 8); z += __shfl_xor(z, 8);
      if (l15 == 0) {
        int ch = 32*ww + 16*t + 4*quad + r;
        atomicAdd(&SS[ch], s); atomicAdd(&SQ[ch], z);
      }
    }
  __syncthreads();
  if (tid < 128) { atomicAdd(&gs3[tid], SS[tid]); atomicAdd(&gq3[tid], SQ[tid]); }
}

// ------------------------------- K7 output ---------------------------------
__global__ __launch_bounds__(256) void pf_out(
    const float* __restrict__ maxv,
    const float* __restrict__ gs3, const float* __restrict__ gq3,
    const float* __restrict__ g3, const float* __restrict__ be3,
    float* __restrict__ out) {
  __shared__ float T[128][17];
  __shared__ float SC[128], SH[128];
  const int tid = threadIdx.x;
  const int b  = blockIdx.x >> 8;
  const int n0 = (blockIdx.x & 255) * 16;
  if (tid < 128) {
    float s, sh; bn_affine(gs3[tid], gq3[tid], g3[tid], be3[tid], s, sh);
    SC[tid] = s; SH[tid] = sh;
  }
  __syncthreads();
  const float4* mv4 = (const float4*)maxv;
  #pragma unroll
  for (int r = 0; r < 2; ++r) {
    int fid = r * 256 + tid;
    int nl = fid >> 5, c4 = fid & 31;
    float4 v = mv4[(size_t)(b*NPTS + n0 + nl)*32 + c4];
    int c = c4 * 4;
    T[c+0][nl] = fmaf(SC[c+0], v.x, SH[c+0]);
    T[c+1][nl] = fmaf(SC[c+1], v.y, SH[c+1]);
    T[c+2][nl] = fmaf(SC[c+2], v.z, SH[c+2]);
    T[c+3][nl] = fmaf(SC[c+3], v.w, SH[c+3]);
  }
  __syncthreads();
  #pragma unroll
  for (int r = 0; r < 2; ++r) {
    int fid = r * 256 + tid;
    int c = fid >> 2, nq = fid & 3;
    float4 o;
    o.x = T[c][nq*4+0]; o.y = T[c][nq*4+1];
    o.z = T[c][nq*4+2]; o.w = T[c][nq*4+3];
    *(float4*)(out + (size_t)b*128*NPTS + (size_t)c*NPTS + n0 + nq*4) = o;
  }
}

// ------------------------------- launcher ----------------------------------
extern "C" void kernel_launch(void* const* d_in, const int* in_sizes, int n_in,
                              void* d_out, int out_size, void* d_ws, size_t ws_size,
                              hipStream_t stream) {
  const float* x   = (const float*)d_in[0];
  const float* W1  = (const float*)d_in[1];
  const float* g1  = (const float*)d_in[3];
  const float* be1 = (const float*)d_in[4];
  const float* W2  = (const float*)d_in[5];
  const float* g2  = (const float*)d_in[7];
  const float* be2 = (const float*)d_in[8];
  const float* W3  = (const float*)d_in[9];
  const float* g3  = (const float*)d_in[11];
  const float* be3 = (const float*)d_in[12];
  float* out = (float*)d_out;

  char* p = (char*)d_ws;
  float4* xp  = (float4*)p;            p += (size_t)BN_ * 16;
  int*    idxb= (int*)p;               p += (size_t)BN_ * KNN * 4;
  float*  stats = (float*)p;           p += 640 * 4;
  float*  aff   = (float*)p;           p += 256 * 4;               // sh1e, shm2
  unsigned short* w1s = (unsigned short*)p; p += 64 * 8 * 2;       // BN1-folded
  unsigned short* w2p = (unsigned short*)p; p += 128 * 64 * 2;     // raw bf16
  unsigned short* w2s = (unsigned short*)p; p += 128 * 64 * 2;     // BN2-folded
  unsigned short* w3p = (unsigned short*)p; p += 128 * 128 * 2;    // raw bf16
  float*  maxv  = (float*)p;           // BN_*128*4 bytes

  float *gm  = stats;                  // 27 moment components
  float *gs2 = stats + 128, *gq2 = stats + 256;
  float *gs3 = stats + 384, *gq3 = stats + 512;
  float *sh1e = aff, *shm2 = aff + 64;

  pf_prep   <<<64,   256, 0, stream>>>(x, xp, stats, W2, W3, w2p, w3p);
  pf_knn    <<<512,  256, 0, stream>>>(xp, idxb);
  pf_mom    <<<64,   256, 0, stream>>>(xp, idxb, gm);
  pf_affine1<<<1,    64,  0, stream>>>(gm, W1, g1, be1, w1s, sh1e);
  pf_stats2 <<<512,  256, 0, stream>>>(xp, idxb, w1s, sh1e, w2p, gs2, gq2);
  pf_affine2<<<32,   256, 0, stream>>>(gs2, gq2, W2, g2, be2, w2s, shm2);
  pf_main   <<<512,  256, 0, stream>>>(xp, idxb, w1s, sh1e, w2s, shm2,
                                       w3p, gs3, gq3, maxv);
  pf_out    <<<1024, 256, 0, stream>>>(maxv, gs3, gq3, g3, be3, out);
}

// Round 16
// 209.170 us; speedup vs baseline: 1.1201x; 1.1201x over previous
//
#include <hip/hip_runtime.h>

// ---------------------------------------------------------------------------
// PatchFeatureExtractor: EdgeConv block — R15 (consolidation).
//   R14's 8q/wave knn spilled (WRITE 17.6MB, FETCH 9.3MB, occupancy 20%) —
//   reverted. This is exact R12 (best verified: 206.7us) + R13's provably
//   safe parallel affine2 (grid 32, removes single-block serial bubble).
//   knn: 4 queries/wave, LDS-atomic compaction (45.0us proven).
//   main/stats2: 32 pts/block, 3-/2-stage software pipelines, 1 barrier/iter.
//   mom: 27 f-moments replace stats1. Biases cancel in train-mode BN.
// ---------------------------------------------------------------------------

typedef __attribute__((ext_vector_type(8)))  short short8;
typedef __attribute__((ext_vector_type(4)))  float floatx4;

#define BATCH 4
#define NPTS  4096
#define KNN   20
#define BN_   (BATCH*NPTS)          // 16384 points
#define CNT   (BATCH*NPTS*KNN)      // 327680 positions

__device__ __forceinline__ unsigned short f2bf(float f) {
  unsigned u = __float_as_uint(f);
  unsigned r = u + 0x7FFFu + ((u >> 16) & 1u);   // RNE
  return (unsigned short)(r >> 16);
}

__device__ __forceinline__ unsigned cvtpk(float lo, float hi) {
  unsigned r;
  asm("v_cvt_pk_bf16_f32 %0, %1, %2" : "=v"(r) : "v"(lo), "v"(hi));
  return r;
}

union PK8 { unsigned u4[4]; short8 s; };

__device__ __forceinline__ void store4bf_relu(unsigned short* dst, floatx4 v) {
  unsigned lo = cvtpk(fmaxf(v[0],0.f), fmaxf(v[1],0.f));
  unsigned hi = cvtpk(fmaxf(v[2],0.f), fmaxf(v[3],0.f));
  *(uint2*)dst = make_uint2(lo, hi);
}

__device__ __forceinline__ unsigned mono(float f) {
  unsigned u = __float_as_uint(f);
  return u ^ ((unsigned)((int)u >> 31) | 0x80000000u);
}

// BN affine from RAW (bias-free) sums: conv bias cancels in train-mode BN
__device__ __forceinline__ void bn_affine(float gsum, float gsq, float gamma,
                                          float beta, float& s, float& sh) {
  const float inv = 1.0f / (float)CNT;
  float mean = gsum * inv;
  float var  = gsq * inv - mean * mean;
  s  = gamma * rsqrtf(var + 1e-5f);
  sh = beta - mean * s;
}

// ------------------------------- K0 prep -----------------------------------
__global__ void pf_prep(const float* __restrict__ x, float4* __restrict__ xp,
                        float* __restrict__ stats,
                        const float* __restrict__ W2, const float* __restrict__ W3,
                        unsigned short* __restrict__ w2p,
                        unsigned short* __restrict__ w3p) {
  int pt = blockIdx.x * 256 + threadIdx.x;      // grid 64 x 256 = 16384
  float x0 = x[pt*3+0], x1 = x[pt*3+1], x2 = x[pt*3+2];
  float xx = x0*x0 + x1*x1 + x2*x2;             // |x|^2 (proven ordering)
  xp[pt] = make_float4(x0, x1, x2, xx);
  if (blockIdx.x == 0)
    for (int i = threadIdx.x; i < 640; i += 256) stats[i] = 0.0f;
  if (blockIdx.x == 1) {
    for (int i = threadIdx.x; i < 128*64;  i += 256) w2p[i] = f2bf(W2[i]);
    for (int i = threadIdx.x; i < 128*128; i += 256) w3p[i] = f2bf(W3[i]);
  }
}

// ------------------------------- K1 knn ------------------------------------
__device__ __forceinline__ float sort_take20th(float v, int lane) {
  #pragma unroll
  for (int k = 2; k <= 64; k <<= 1) {
    #pragma unroll
    for (int j = k >> 1; j >= 1; j >>= 1) {
      float o = __shfl_xor(v, j);
      bool keepmax = (((lane & j) == 0) == ((lane & k) == 0));
      v = keepmax ? fmaxf(v, o) : fminf(v, o);
    }
  }
  return __shfl(v, 19);
}

__device__ __forceinline__ unsigned long long sort64_desc(unsigned long long v,
                                                          int lane) {
  #pragma unroll
  for (int k = 2; k <= 64; k <<= 1) {
    #pragma unroll
    for (int j = k >> 1; j >= 1; j >>= 1) {
      unsigned long long o = __shfl_xor(v, j);
      bool keepmax = (((lane & j) == 0) == ((lane & k) == 0));
      unsigned long long hi = v > o ? v : o;
      unsigned long long lo = v > o ? o : v;
      v = keepmax ? hi : lo;
    }
  }
  return v;
}

// grid 1024: 16 queries/block, 4 per wave (R10/R12-proven configuration).
__global__ __launch_bounds__(256) void pf_knn(const float4* __restrict__ xp,
                                              int* __restrict__ idxb) {
  __shared__ unsigned long long lst[16][128];   // 16 KB
  __shared__ int lcnt[16];
  const int tid  = threadIdx.x;
  const int lane = tid & 63;
  const int w    = tid >> 6;
  const int b    = blockIdx.x >> 8;                    // 256 blocks/batch
  const int nb   = (blockIdx.x & 255) * 16 + w * 4;    // 4 queries per wave
  const float4* xb = xp + b * NPTS;

  float4 q0 = xb[nb], q1 = xb[nb+1], q2 = xb[nb+2], q3 = xb[nb+3];

  // pass 1: per-lane max pd over its 64-candidate strip
  float mx0=-3.0e38f, mx1=-3.0e38f, mx2=-3.0e38f, mx3=-3.0e38f;
  for (int j0 = 0; j0 < NPTS; j0 += 64) {
    float4 c = xb[j0 + lane];
    float d0 = fmaf(q0.x,c.x, fmaf(q0.y,c.y, q0.z*c.z));
    float d1 = fmaf(q1.x,c.x, fmaf(q1.y,c.y, q1.z*c.z));
    float d2 = fmaf(q2.x,c.x, fmaf(q2.y,c.y, q2.z*c.z));
    float d3 = fmaf(q3.x,c.x, fmaf(q3.y,c.y, q3.z*c.z));
    mx0 = fmaxf(mx0, fmaf(2.f,d0,-q0.w) - c.w);
    mx1 = fmaxf(mx1, fmaf(2.f,d1,-q1.w) - c.w);
    mx2 = fmaxf(mx2, fmaf(2.f,d2,-q2.w) - c.w);
    mx3 = fmaxf(mx3, fmaf(2.f,d3,-q3.w) - c.w);
  }
  // T = 20th largest of the 64 lane-maxes: provably <= true 20th-largest pd
  float T0 = sort_take20th(mx0, lane);
  float T1 = sort_take20th(mx1, lane);
  float T2 = sort_take20th(mx2, lane);
  float T3 = sort_take20th(mx3, lane);

  if (lane < 4) lcnt[w*4 + lane] = 0;
  __syncthreads();

  // pass 2: compact candidates with pd >= T (order carried in 64-bit key)
  for (int j0 = 0; j0 < NPTS; j0 += 64) {
    float4 c = xb[j0 + lane];
    float d0 = fmaf(q0.x,c.x, fmaf(q0.y,c.y, q0.z*c.z));
    float d1 = fmaf(q1.x,c.x, fmaf(q1.y,c.y, q1.z*c.z));
    float d2 = fmaf(q2.x,c.x, fmaf(q2.y,c.y, q2.z*c.z));
    float d3 = fmaf(q3.x,c.x, fmaf(q3.y,c.y, q3.z*c.z));
    float p0 = fmaf(2.f,d0,-q0.w) - c.w;
    float p1 = fmaf(2.f,d1,-q1.w) - c.w;
    float p2 = fmaf(2.f,d2,-q2.w) - c.w;
    float p3 = fmaf(2.f,d3,-q3.w) - c.w;
    unsigned long long keybase = (unsigned long long)(4095 - (j0 + lane));
    if (p0 >= T0) {
      int o = atomicAdd(&lcnt[w*4+0], 1);
      if (o < 128) lst[w*4+0][o] = ((unsigned long long)mono(p0) << 32) | keybase;
    }
    if (p1 >= T1) {
      int o = atomicAdd(&lcnt[w*4+1], 1);
      if (o < 128) lst[w*4+1][o] = ((unsigned long long)mono(p1) << 32) | keybase;
    }
    if (p2 >= T2) {
      int o = atomicAdd(&lcnt[w*4+2], 1);
      if (o < 128) lst[w*4+2][o] = ((unsigned long long)mono(p2) << 32) | keybase;
    }
    if (p3 >= T3) {
      int o = atomicAdd(&lcnt[w*4+3], 1);
      if (o < 128) lst[w*4+3][o] = ((unsigned long long)mono(p3) << 32) | keybase;
    }
  }

  // exact top-20 per query
  #pragma unroll 1
  for (int i = 0; i < 4; ++i) {
    const int li = w*4 + i;
    const int cn = lcnt[li];
    const int outbase = (b * NPTS + nb + i) * KNN;
    if (cn <= 64) {                       // common case: one sort
      unsigned long long v = (lane < cn) ? lst[li][lane] : 0ull;
      v = sort64_desc(v, lane);
      if (lane < KNN) idxb[outbase + lane] = 4095 - (int)(v & 0xFFFFFFFFull);
    } else if (cn <= 128) {               // rare: 20-round argmax on 2 regs
      unsigned long long e0 = lst[li][lane];
      unsigned long long e1 = (lane + 64 < cn) ? lst[li][lane + 64] : 0ull;
      #pragma unroll 1
      for (int r = 0; r < KNN; ++r) {
        unsigned long long m = e0 > e1 ? e0 : e1;
        #pragma unroll
        for (int o = 32; o; o >>= 1) {
          unsigned long long t = __shfl_xor(m, o);
          m = t > m ? t : m;
        }
        if (lane == 0) idxb[outbase + r] = 4095 - (int)(m & 0xFFFFFFFFull);
        if (e0 == m) e0 = 0ull; else if (e1 == m) e1 = 0ull;
      }
    } else {                              // ~never: exact full re-scan
      const float4 qq = (i == 0) ? q0 : (i == 1) ? q1 : (i == 2) ? q2 : q3;
      unsigned long long prev = ~0ull;
      #pragma unroll 1
      for (int r = 0; r < KNN; ++r) {
        unsigned long long best = 0ull;
        for (int j0 = 0; j0 < NPTS; j0 += 64) {
          float4 c = xb[j0 + lane];
          float dd = fmaf(qq.x,c.x, fmaf(qq.y,c.y, qq.z*c.z));
          float pd = fmaf(2.f,dd,-qq.w) - c.w;
          unsigned long long key = ((unsigned long long)mono(pd) << 32) |
                                   (unsigned long long)(4095 - (j0 + lane));
          if (key < prev && key > best) best = key;
        }
        #pragma unroll
        for (int o = 32; o; o >>= 1) {
          unsigned long long t = __shfl_xor(best, o);
          best = t > best ? t : best;
        }
        if (lane == 0) idxb[outbase + r] = 4095 - (int)(best & 0xFFFFFFFFull);
        prev = best;
      }
    }
  }
}

// ------------------------------- K2 moments --------------------------------
__global__ __launch_bounds__(256) void pf_mom(
    const float4* __restrict__ xp, const int* __restrict__ idxb,
    float* __restrict__ gm) {
  __shared__ float WM[4][27];
  const int tid = threadIdx.x, lane = tid & 63, w = tid >> 6;
  const int pt = blockIdx.x * 256 + tid;
  const float4 xi = xp[pt];
  const int ib = (pt >> 12) << 12;

  int idx[KNN];
  const int4* ip = (const int4*)(idxb + pt*KNN);
  #pragma unroll
  for (int q = 0; q < 5; ++q) {
    int4 v = ip[q];
    idx[q*4+0]=v.x; idx[q*4+1]=v.y; idx[q*4+2]=v.z; idx[q*4+3]=v.w;
  }
  float sj0=0,sj1=0,sj2=0, p0=0,p1=0,p2=0,p3=0,p4=0,p5=0;
  #pragma unroll
  for (int kk = 0; kk < KNN; ++kk) {
    float4 xj = xp[ib + idx[kk]];
    sj0 += xj.x; sj1 += xj.y; sj2 += xj.z;
    p0 = fmaf(xj.x,xj.x,p0); p1 = fmaf(xj.x,xj.y,p1); p2 = fmaf(xj.x,xj.z,p2);
    p3 = fmaf(xj.y,xj.y,p3); p4 = fmaf(xj.y,xj.z,p4); p5 = fmaf(xj.z,xj.z,p5);
  }
  float m[27];
  m[0]=sj0; m[1]=sj1; m[2]=sj2;
  m[3]=20.f*xi.x; m[4]=20.f*xi.y; m[5]=20.f*xi.z;
  m[6]=p0; m[7]=p1; m[8]=p2; m[9]=p3; m[10]=p4; m[11]=p5;
  m[12]=20.f*xi.x*xi.x; m[13]=20.f*xi.x*xi.y; m[14]=20.f*xi.x*xi.z;
  m[15]=20.f*xi.y*xi.y; m[16]=20.f*xi.y*xi.z; m[17]=20.f*xi.z*xi.z;
  m[18]=sj0*xi.x; m[19]=sj0*xi.y; m[20]=sj0*xi.z;
  m[21]=sj1*xi.x; m[22]=sj1*xi.y; m[23]=sj1*xi.z;
  m[24]=sj2*xi.x; m[25]=sj2*xi.y; m[26]=sj2*xi.z;
  #pragma unroll
  for (int c = 0; c < 27; ++c) {
    float v = m[c];
    #pragma unroll
    for (int o = 32; o; o >>= 1) v += __shfl_xor(v, o);
    m[c] = v;
  }
  if (lane == 0)
    #pragma unroll
    for (int c = 0; c < 27; ++c) WM[w][c] = m[c];
  __syncthreads();
  if (tid < 27) atomicAdd(&gm[tid], WM[0][tid]+WM[1][tid]+WM[2][tid]+WM[3][tid]);
}

// ------------------------------- K3 affine1 --------------------------------
__global__ void pf_affine1(const float* __restrict__ gm,
                           const float* __restrict__ W1,
                           const float* __restrict__ g1,
                           const float* __restrict__ be1,
                           unsigned short* __restrict__ w1s,
                           float* __restrict__ sh1e) {
  int c = threadIdx.x;
  if (c >= 64) return;
  const float* wr = W1 + c*6;
  const float wa[3] = {wr[0], wr[1], wr[2]};
  const float wb[3] = {wr[3], wr[4], wr[5]};
  const int si0[9] = {0,1,2, 1,3,4, 2,4,5};
  float syf = 0.f, sy2 = 0.f;
  #pragma unroll
  for (int a = 0; a < 3; ++a)
    syf += wa[a]*(gm[a] - gm[3+a]) + wb[a]*gm[3+a];
  #pragma unroll
  for (int a = 0; a < 3; ++a)
    #pragma unroll
    for (int bq = 0; bq < 3; ++bq) {
      int k = a*3 + bq, kt = bq*3 + a;
      float pjj = gm[6 + si0[k]], pii = gm[12 + si0[k]];
      float cc = gm[18 + k], ct = gm[18 + kt];
      float uu = pjj - cc - ct + pii;
      float uv = cc - pii;
      sy2 += wa[a]*wa[bq]*uu + 2.f*wa[a]*wb[bq]*uv + wb[a]*wb[bq]*pii;
    }
  const float inv = 1.0f / (float)CNT;
  float mean = syf * inv;
  float var  = sy2 * inv - mean * mean;
  float s  = g1[c] * rsqrtf(var + 1e-5f);
  sh1e[c]  = be1[c] - mean * s;
  unsigned short* o = w1s + c*8;
  o[0]=f2bf(s*wa[0]); o[1]=f2bf(s*wa[1]); o[2]=f2bf(s*wa[2]);
  o[3]=f2bf(s*wb[0]); o[4]=f2bf(s*wb[1]); o[5]=f2bf(s*wb[2]);
  o[6]=0; o[7]=0;
}

// ------------------------------- K5 affine2 --------------------------------
// grid 32 x 256 = 8192 threads, one W2 element each (redundant bn_affine).
__global__ void pf_affine2(const float* __restrict__ gs2,
                           const float* __restrict__ gq2,
                           const float* __restrict__ W2,
                           const float* __restrict__ g2,
                           const float* __restrict__ be2,
                           unsigned short* __restrict__ w2s,
                           float* __restrict__ shm2) {
  int g = blockIdx.x * 256 + threadIdx.x;
  if (g >= 128*64) return;
  int c = g >> 6, j = g & 63;
  float s, sh; bn_affine(gs2[c], gq2[c], g2[c], be2[c], s, sh);
  if (j == 0) shm2[c] = sh;
  w2s[g] = f2bf(s * W2[g]);
}

// ------------------------------- K4 stats2 ---------------------------------
// grid 512, 32 pts/block (two point-halves), 2-stage pipeline, 1 barrier/iter.
__global__ __launch_bounds__(256, 3) void pf_stats2(
    const float4* __restrict__ xp, const int* __restrict__ idxb,
    const unsigned short* __restrict__ w1s, const float* __restrict__ sh1e,
    const unsigned short* __restrict__ w2p,
    float* __restrict__ gs2, float* __restrict__ gq2) {
  __shared__ __align__(16) short8 AF[KNN][32];             // 10 KB
  __shared__ __align__(16) unsigned short H1[2][32][72];   // 9 KB
  __shared__ float SS[128], SQ[128];

  const int tid = threadIdx.x;
  const int lane = tid & 63, ww = tid >> 6;
  const int l15 = lane & 15, quad = lane >> 4;
  const int pt0 = blockIdx.x * 32;

  if (tid < 128) { SS[tid] = 0.f; SQ[tid] = 0.f; }

  for (int u = tid; u < 32*KNN; u += 256) {
    int kk = u >> 5, pp = u & 31;
    int pt = pt0 + pp;
    float4 xi = xp[pt];
    float4 xj = xp[((pt >> 12) << 12) + idxb[pt*KNN + kk]];
    PK8 U;
    U.u4[0] = cvtpk(xj.x-xi.x, xj.y-xi.y);
    U.u4[1] = cvtpk(xj.z-xi.z, xi.x);
    U.u4[2] = cvtpk(xi.y, xi.z);
    U.u4[3] = 0;
    AF[kk][pp] = U.s;
  }

  short8 w1f = *(const short8*)(w1s + (16*ww + l15)*8);
  floatx4 sh1v;
  #pragma unroll
  for (int r = 0; r < 4; ++r) sh1v[r] = sh1e[16*ww + 4*quad + r];

  short8 w2f[2][2];
  #pragma unroll
  for (int ks = 0; ks < 2; ++ks)
    #pragma unroll
    for (int t = 0; t < 2; ++t)
      w2f[ks][t] = *(const short8*)(w2p + (32*ww + 16*t + l15)*64 + 32*ks + quad*8);

  float sum[2][2][4] = {{{0,0,0,0},{0,0,0,0}},{{0,0,0,0},{0,0,0,0}}};
  float sq [2][2][4] = {{{0,0,0,0},{0,0,0,0}},{{0,0,0,0},{0,0,0,0}}};
  const short8 z8 = {0,0,0,0,0,0,0,0};
  __syncthreads();

  #pragma unroll 1
  for (int k = 0; k < KNN + 1; ++k) {
    // stage 2: L2(k-1) for both point-halves
    if (k >= 1) {
      #pragma unroll
      for (int ph = 0; ph < 2; ++ph) {
        floatx4 acc2[2] = {{0,0,0,0},{0,0,0,0}};
        #pragma unroll
        for (int ks = 0; ks < 2; ++ks) {
          short8 a = *(const short8*)&H1[(k-1) & 1][ph*16 + l15][ks*32 + quad*8];
          #pragma unroll
          for (int t = 0; t < 2; ++t)
            acc2[t] = __builtin_amdgcn_mfma_f32_16x16x32_bf16(w2f[ks][t], a, acc2[t], 0,0,0);
        }
        #pragma unroll
        for (int t = 0; t < 2; ++t)
          #pragma unroll
          for (int r = 0; r < 4; ++r) {
            float v = acc2[t][r];          // raw conv2 (bias cancels in BN)
            sum[ph][t][r] += v; sq[ph][t][r] = fmaf(v, v, sq[ph][t][r]);
          }
      }
    }
    // stage 1: L1(k) for both point-halves -> H1[k&1]
    if (k < KNN) {
      #pragma unroll
      for (int ph = 0; ph < 2; ++ph) {
        short8 a0 = z8;
        if (quad == 0) a0 = AF[k][ph*16 + l15];
        floatx4 c0 = sh1v;
        c0 = __builtin_amdgcn_mfma_f32_16x16x32_bf16(w1f, a0, c0, 0,0,0);
        store4bf_relu(&H1[k & 1][ph*16 + l15][16*ww + 4*quad], c0);
      }
    }
    __syncthreads();                       // single barrier per iteration
  }
  #pragma unroll
  for (int t = 0; t < 2; ++t)
    #pragma unroll
    for (int r = 0; r < 4; ++r) {
      float s = sum[0][t][r] + sum[1][t][r];
      float z = sq[0][t][r] + sq[1][t][r];
      s += __shfl_xor(s, 1); z += __shfl_xor(z, 1);
      s += __shfl_xor(s, 2); z += __shfl_xor(z, 2);
      s += __shfl_xor(s, 4); z += __shfl_xor(z, 4);
      s += __shfl_xor(s, 8); z += __shfl_xor(z, 8);
      if (l15 == 0) {
        int ch = 32*ww + 16*t + 4*quad + r;
        atomicAdd(&SS[ch], s); atomicAdd(&SQ[ch], z);
      }
    }
  __syncthreads();
  if (tid < 128) { atomicAdd(&gs2[tid], SS[tid]); atomicAdd(&gq2[tid], SQ[tid]); }
}

// ------------------------------- K6 main -----------------------------------
// grid 512, 32 pts/block (two point-halves), 3-stage pipeline, 1 barrier/iter.
__global__ __launch_bounds__(256, 2) void pf_main(
    const float4* __restrict__ xp, const int* __restrict__ idxb,
    const unsigned short* __restrict__ w1s, const float* __restrict__ sh1e,
    const unsigned short* __restrict__ w2s, const float* __restrict__ shm2,
    const unsigned short* __restrict__ w3p,
    float* __restrict__ gs3, float* __restrict__ gq3,
    float* __restrict__ maxv) {
  __shared__ __align__(16) short8 AF[KNN][32];             // 10 KB
  __shared__ __align__(16) unsigned short H1[2][32][72];   // 9 KB
  __shared__ __align__(16) unsigned short H2[2][32][136];  // 17 KB
  __shared__ float SS[128], SQ[128];

  const int tid = threadIdx.x;
  const int lane = tid & 63, ww = tid >> 6;
  const int l15 = lane & 15, quad = lane >> 4;
  const int pt0 = blockIdx.x * 32;

  if (tid < 128) { SS[tid] = 0.f; SQ[tid] = 0.f; }

  for (int u = tid; u < 32*KNN; u += 256) {
    int kk = u >> 5, pp = u & 31;
    int pt = pt0 + pp;
    float4 xi = xp[pt];
    float4 xj = xp[((pt >> 12) << 12) + idxb[pt*KNN + kk]];
    PK8 U;
    U.u4[0] = cvtpk(xj.x-xi.x, xj.y-xi.y);
    U.u4[1] = cvtpk(xj.z-xi.z, xi.x);
    U.u4[2] = cvtpk(xi.y, xi.z);
    U.u4[3] = 0;
    AF[kk][pp] = U.s;
  }

  short8 w1f = *(const short8*)(w1s + (16*ww + l15)*8);
  floatx4 sh1v;
  #pragma unroll
  for (int r = 0; r < 4; ++r) sh1v[r] = sh1e[16*ww + 4*quad + r];
  short8 w2f[2][2];
  #pragma unroll
  for (int ks = 0; ks < 2; ++ks)
    #pragma unroll
    for (int t = 0; t < 2; ++t)
      w2f[ks][t] = *(const short8*)(w2s + (32*ww + 16*t + l15)*64 + 32*ks + quad*8);
  floatx4 sh2v[2];
  #pragma unroll
  for (int t = 0; t < 2; ++t)
    #pragma unroll
    for (int r = 0; r < 4; ++r)
      sh2v[t][r] = shm2[32*ww + 16*t + 4*quad + r];
  short8 w3f[4][2];
  #pragma unroll
  for (int ks = 0; ks < 4; ++ks)
    #pragma unroll
    for (int t = 0; t < 2; ++t)
      w3f[ks][t] = *(const short8*)(w3p + (32*ww + 16*t + l15)*128 + 32*ks + quad*8);

  float sum[2][2][4] = {{{0,0,0,0},{0,0,0,0}},{{0,0,0,0},{0,0,0,0}}};
  float sq [2][2][4] = {{{0,0,0,0},{0,0,0,0}},{{0,0,0,0},{0,0,0,0}}};
  float mx [2][2][4];
  #pragma unroll
  for (int ph = 0; ph < 2; ++ph)
    #pragma unroll
    for (int t = 0; t < 2; ++t)
      #pragma unroll
      for (int r = 0; r < 4; ++r) mx[ph][t][r] = -3.0e38f;

  const short8 z8 = {0,0,0,0,0,0,0,0};
  __syncthreads();

  #pragma unroll 1
  for (int k = 0; k < KNN + 2; ++k) {
    // ---- stage 3: L3(k-2) from H2[(k-2)&1] == H2[k&1] ----
    if (k >= 2) {
      #pragma unroll
      for (int ph = 0; ph < 2; ++ph) {
        floatx4 acc3[2] = {{0,0,0,0},{0,0,0,0}};
        #pragma unroll
        for (int ks = 0; ks < 4; ++ks) {
          short8 a = *(const short8*)&H2[k & 1][ph*16 + l15][ks*32 + quad*8];
          #pragma unroll
          for (int t = 0; t < 2; ++t)
            acc3[t] = __builtin_amdgcn_mfma_f32_16x16x32_bf16(w3f[ks][t], a, acc3[t], 0,0,0);
        }
        #pragma unroll
        for (int t = 0; t < 2; ++t)
          #pragma unroll
          for (int r = 0; r < 4; ++r) {
            float v = acc3[t][r];
            sum[ph][t][r] += v; sq[ph][t][r] = fmaf(v, v, sq[ph][t][r]);
            mx[ph][t][r] = fmaxf(mx[ph][t][r], v);
          }
      }
    }
    // ---- stage 2: L2(k-1) from H1[(k-1)&1] -> H2[(k-1)&1] ----
    if (k >= 1 && k < KNN + 1) {
      #pragma unroll
      for (int ph = 0; ph < 2; ++ph) {
        floatx4 acc2[2] = {sh2v[0], sh2v[1]};
        #pragma unroll
        for (int ks = 0; ks < 2; ++ks) {
          short8 a = *(const short8*)&H1[(k-1) & 1][ph*16 + l15][ks*32 + quad*8];
          #pragma unroll
          for (int t = 0; t < 2; ++t)
            acc2[t] = __builtin_amdgcn_mfma_f32_16x16x32_bf16(w2f[ks][t], a, acc2[t], 0,0,0);
        }
        #pragma unroll
        for (int t = 0; t < 2; ++t)
          store4bf_relu(&H2[(k-1) & 1][ph*16 + l15][32*ww + 16*t + 4*quad], acc2[t]);
      }
    }
    // ---- stage 1: L1(k) -> H1[k&1] ----
    if (k < KNN) {
      #pragma unroll
      for (int ph = 0; ph < 2; ++ph) {
        short8 a0 = z8;
        if (quad == 0) a0 = AF[k][ph*16 + l15];
        floatx4 acc1 = sh1v;
        acc1 = __builtin_amdgcn_mfma_f32_16x16x32_bf16(w1f, a0, acc1, 0,0,0);
        store4bf_relu(&H1[k & 1][ph*16 + l15][16*ww + 4*quad], acc1);
      }
    }
    __syncthreads();                       // single barrier per iteration
  }

  #pragma unroll
  for (int ph = 0; ph < 2; ++ph)
    #pragma unroll
    for (int t = 0; t < 2; ++t) {
      int ch0 = 32*ww + 16*t + 4*quad;
      float4 o = make_float4(mx[ph][t][0], mx[ph][t][1], mx[ph][t][2], mx[ph][t][3]);
      *(float4*)&maxv[(size_t)(pt0 + ph*16 + l15)*128 + ch0] = o;
    }
  #pragma unroll
  for (int t = 0; t < 2; ++t)
    #pragma unroll
    for (int r = 0; r < 4; ++r) {
      float s = sum[0][t][r] + sum[1][t][r];
      float z = sq[0][t][r] + sq[1][t][r];
      s += __shfl_xor(s, 1); z += __shfl_xor(z, 1);
      s += __shfl_xor(s, 2); z += __shfl_xor(z, 2);
      s += __shfl_xor(s, 4); z += __shfl_xor(z, 4);
      s += __shfl_xor(s, 8); z += __shfl_xor(z, 8);
      if (l15 == 0) {
        int ch = 32*ww + 16*t + 4*quad + r;
        atomicAdd(&SS[ch], s); atomicAdd(&SQ[ch], z);
      }
    }
  __syncthreads();
  if (tid < 128) { atomicAdd(&gs3[tid], SS[tid]); atomicAdd(&gq3[tid], SQ[tid]); }
}

// ------------------------------- K7 output ---------------------------------
__global__ __launch_bounds__(256) void pf_out(
    const float* __restrict__ maxv,
    const float* __restrict__ gs3, const float* __restrict__ gq3,
    const float* __restrict__ g3, const float* __restrict__ be3,
    float* __restrict__ out) {
  __shared__ float T[128][17];
  __shared__ float SC[128], SH[128];
  const int tid = threadIdx.x;
  const int b  = blockIdx.x >> 8;
  const int n0 = (blockIdx.x & 255) * 16;
  if (tid < 128) {
    float s, sh; bn_affine(gs3[tid], gq3[tid], g3[tid], be3[tid], s, sh);
    SC[tid] = s; SH[tid] = sh;
  }
  __syncthreads();
  const float4* mv4 = (const float4*)maxv;
  #pragma unroll
  for (int r = 0; r < 2; ++r) {
    int fid = r * 256 + tid;
    int nl = fid >> 5, c4 = fid & 31;
    float4 v = mv4[(size_t)(b*NPTS + n0 + nl)*32 + c4];
    int c = c4 * 4;
    T[c+0][nl] = fmaf(SC[c+0], v.x, SH[c+0]);
    T[c+1][nl] = fmaf(SC[c+1], v.y, SH[c+1]);
    T[c+2][nl] = fmaf(SC[c+2], v.z, SH[c+2]);
    T[c+3][nl] = fmaf(SC[c+3], v.w, SH[c+3]);
  }
  __syncthreads();
  #pragma unroll
  for (int r = 0; r < 2; ++r) {
    int fid = r * 256 + tid;
    int c = fid >> 2, nq = fid & 3;
    float4 o;
    o.x = T[c][nq*4+0]; o.y = T[c][nq*4+1];
    o.z = T[c][nq*4+2]; o.w = T[c][nq*4+3];
    *(float4*)(out + (size_t)b*128*NPTS + (size_t)c*NPTS + n0 + nq*4) = o;
  }
}

// ------------------------------- launcher ----------------------------------
extern "C" void kernel_launch(void* const* d_in, const int* in_sizes, int n_in,
                              void* d_out, int out_size, void* d_ws, size_t ws_size,
                              hipStream_t stream) {
  const float* x   = (const float*)d_in[0];
  const float* W1  = (const float*)d_in[1];
  const float* g1  = (const float*)d_in[3];
  const float* be1 = (const float*)d_in[4];
  const float* W2  = (const float*)d_in[5];
  const float* g2  = (const float*)d_in[7];
  const float* be2 = (const float*)d_in[8];
  const float* W3  = (const float*)d_in[9];
  const float* g3  = (const float*)d_in[11];
  const float* be3 = (const float*)d_in[12];
  float* out = (float*)d_out;

  char* p = (char*)d_ws;
  float4* xp  = (float4*)p;            p += (size_t)BN_ * 16;
  int*    idxb= (int*)p;               p += (size_t)BN_ * KNN * 4;
  float*  stats = (float*)p;           p += 640 * 4;
  float*  aff   = (float*)p;           p += 256 * 4;               // sh1e, shm2
  unsigned short* w1s = (unsigned short*)p; p += 64 * 8 * 2;       // BN1-folded
  unsigned short* w2p = (unsigned short*)p; p += 128 * 64 * 2;     // raw bf16
  unsigned short* w2s = (unsigned short*)p; p += 128 * 64 * 2;     // BN2-folded
  unsigned short* w3p = (unsigned short*)p; p += 128 * 128 * 2;    // raw bf16
  float*  maxv  = (float*)p;           // BN_*128*4 bytes

  float *gm  = stats;                  // 27 moment components
  float *gs2 = stats + 128, *gq2 = stats + 256;
  float *gs3 = stats + 384, *gq3 = stats + 512;
  float *sh1e = aff, *shm2 = aff + 64;

  pf_prep   <<<64,   256, 0, stream>>>(x, xp, stats, W2, W3, w2p, w3p);
  pf_knn    <<<1024, 256, 0, stream>>>(xp, idxb);
  pf_mom    <<<64,   256, 0, stream>>>(xp, idxb, gm);
  pf_affine1<<<1,    64,  0, stream>>>(gm, W1, g1, be1, w1s, sh1e);
  pf_stats2 <<<512,  256, 0, stream>>>(xp, idxb, w1s, sh1e, w2p, gs2, gq2);
  pf_affine2<<<32,   256, 0, stream>>>(gs2, gq2, W2, g2, be2, w2s, shm2);
  pf_main   <<<512,  256, 0, stream>>>(xp, idxb, w1s, sh1e, w2s, shm2,
                                       w3p, gs3, gq3, maxv);
  pf_out    <<<1024, 256, 0, stream>>>(maxv, gs3, gq3, g3, be3, out);
}

// Round 17
// 206.401 us; speedup vs baseline: 1.1351x; 1.0134x over previous
//
#include <hip/hip_runtime.h>

// ---------------------------------------------------------------------------
// PatchFeatureExtractor: EdgeConv block — R16 (final consolidation).
//   = R15 (best-known ~207us config) with pf_affine2 eliminated: BN2 fold
//   inlined into pf_main preamble (R6-proven simple-bn_affine pattern;
//   cvtpk(s*W2) is RNE == f2bf(s*W2) -> bit-identical results). Saves one
//   launch + gap + the w2s buffer round-trip.
//   knn: 4 queries/wave, LDS-atomic compaction (proven optimum).
//   main/stats2: 32 pts/block, 3-/2-stage software pipelines, 1 barrier/iter.
//   mom: 27 f-moments replace stats1. Conv biases cancel in train-mode BN.
// ---------------------------------------------------------------------------

typedef __attribute__((ext_vector_type(8)))  short short8;
typedef __attribute__((ext_vector_type(4)))  float floatx4;

#define BATCH 4
#define NPTS  4096
#define KNN   20
#define BN_   (BATCH*NPTS)          // 16384 points
#define CNT   (BATCH*NPTS*KNN)      // 327680 positions

__device__ __forceinline__ unsigned short f2bf(float f) {
  unsigned u = __float_as_uint(f);
  unsigned r = u + 0x7FFFu + ((u >> 16) & 1u);   // RNE
  return (unsigned short)(r >> 16);
}

__device__ __forceinline__ unsigned cvtpk(float lo, float hi) {
  unsigned r;
  asm("v_cvt_pk_bf16_f32 %0, %1, %2" : "=v"(r) : "v"(lo), "v"(hi));
  return r;
}

union PK8 { unsigned u4[4]; short8 s; };

__device__ __forceinline__ void store4bf_relu(unsigned short* dst, floatx4 v) {
  unsigned lo = cvtpk(fmaxf(v[0],0.f), fmaxf(v[1],0.f));
  unsigned hi = cvtpk(fmaxf(v[2],0.f), fmaxf(v[3],0.f));
  *(uint2*)dst = make_uint2(lo, hi);
}

__device__ __forceinline__ unsigned mono(float f) {
  unsigned u = __float_as_uint(f);
  return u ^ ((unsigned)((int)u >> 31) | 0x80000000u);
}

// BN affine from RAW (bias-free) sums: conv bias cancels in train-mode BN
__device__ __forceinline__ void bn_affine(float gsum, float gsq, float gamma,
                                          float beta, float& s, float& sh) {
  const float inv = 1.0f / (float)CNT;
  float mean = gsum * inv;
  float var  = gsq * inv - mean * mean;
  s  = gamma * rsqrtf(var + 1e-5f);
  sh = beta - mean * s;
}

// ------------------------------- K0 prep -----------------------------------
__global__ void pf_prep(const float* __restrict__ x, float4* __restrict__ xp,
                        float* __restrict__ stats,
                        const float* __restrict__ W2, const float* __restrict__ W3,
                        unsigned short* __restrict__ w2p,
                        unsigned short* __restrict__ w3p) {
  int pt = blockIdx.x * 256 + threadIdx.x;      // grid 64 x 256 = 16384
  float x0 = x[pt*3+0], x1 = x[pt*3+1], x2 = x[pt*3+2];
  float xx = x0*x0 + x1*x1 + x2*x2;             // |x|^2 (proven ordering)
  xp[pt] = make_float4(x0, x1, x2, xx);
  if (blockIdx.x == 0)
    for (int i = threadIdx.x; i < 640; i += 256) stats[i] = 0.0f;
  if (blockIdx.x == 1) {
    for (int i = threadIdx.x; i < 128*64;  i += 256) w2p[i] = f2bf(W2[i]);
    for (int i = threadIdx.x; i < 128*128; i += 256) w3p[i] = f2bf(W3[i]);
  }
}

// ------------------------------- K1 knn ------------------------------------
__device__ __forceinline__ float sort_take20th(float v, int lane) {
  #pragma unroll
  for (int k = 2; k <= 64; k <<= 1) {
    #pragma unroll
    for (int j = k >> 1; j >= 1; j >>= 1) {
      float o = __shfl_xor(v, j);
      bool keepmax = (((lane & j) == 0) == ((lane & k) == 0));
      v = keepmax ? fmaxf(v, o) : fminf(v, o);
    }
  }
  return __shfl(v, 19);
}

__device__ __forceinline__ unsigned long long sort64_desc(unsigned long long v,
                                                          int lane) {
  #pragma unroll
  for (int k = 2; k <= 64; k <<= 1) {
    #pragma unroll
    for (int j = k >> 1; j >= 1; j >>= 1) {
      unsigned long long o = __shfl_xor(v, j);
      bool keepmax = (((lane & j) == 0) == ((lane & k) == 0));
      unsigned long long hi = v > o ? v : o;
      unsigned long long lo = v > o ? o : v;
      v = keepmax ? hi : lo;
    }
  }
  return v;
}

// grid 1024: 16 queries/block, 4 per wave (proven configuration).
__global__ __launch_bounds__(256) void pf_knn(const float4* __restrict__ xp,
                                              int* __restrict__ idxb) {
  __shared__ unsigned long long lst[16][128];   // 16 KB
  __shared__ int lcnt[16];
  const int tid  = threadIdx.x;
  const int lane = tid & 63;
  const int w    = tid >> 6;
  const int b    = blockIdx.x >> 8;                    // 256 blocks/batch
  const int nb   = (blockIdx.x & 255) * 16 + w * 4;    // 4 queries per wave
  const float4* xb = xp + b * NPTS;

  float4 q0 = xb[nb], q1 = xb[nb+1], q2 = xb[nb+2], q3 = xb[nb+3];

  // pass 1: per-lane max pd over its 64-candidate strip
  float mx0=-3.0e38f, mx1=-3.0e38f, mx2=-3.0e38f, mx3=-3.0e38f;
  for (int j0 = 0; j0 < NPTS; j0 += 64) {
    float4 c = xb[j0 + lane];
    float d0 = fmaf(q0.x,c.x, fmaf(q0.y,c.y, q0.z*c.z));
    float d1 = fmaf(q1.x,c.x, fmaf(q1.y,c.y, q1.z*c.z));
    float d2 = fmaf(q2.x,c.x, fmaf(q2.y,c.y, q2.z*c.z));
    float d3 = fmaf(q3.x,c.x, fmaf(q3.y,c.y, q3.z*c.z));
    mx0 = fmaxf(mx0, fmaf(2.f,d0,-q0.w) - c.w);
    mx1 = fmaxf(mx1, fmaf(2.f,d1,-q1.w) - c.w);
    mx2 = fmaxf(mx2, fmaf(2.f,d2,-q2.w) - c.w);
    mx3 = fmaxf(mx3, fmaf(2.f,d3,-q3.w) - c.w);
  }
  // T = 20th largest of the 64 lane-maxes: provably <= true 20th-largest pd
  float T0 = sort_take20th(mx0, lane);
  float T1 = sort_take20th(mx1, lane);
  float T2 = sort_take20th(mx2, lane);
  float T3 = sort_take20th(mx3, lane);

  if (lane < 4) lcnt[w*4 + lane] = 0;
  __syncthreads();

  // pass 2: compact candidates with pd >= T (order carried in 64-bit key)
  for (int j0 = 0; j0 < NPTS; j0 += 64) {
    float4 c = xb[j0 + lane];
    float d0 = fmaf(q0.x,c.x, fmaf(q0.y,c.y, q0.z*c.z));
    float d1 = fmaf(q1.x,c.x, fmaf(q1.y,c.y, q1.z*c.z));
    float d2 = fmaf(q2.x,c.x, fmaf(q2.y,c.y, q2.z*c.z));
    float d3 = fmaf(q3.x,c.x, fmaf(q3.y,c.y, q3.z*c.z));
    float p0 = fmaf(2.f,d0,-q0.w) - c.w;
    float p1 = fmaf(2.f,d1,-q1.w) - c.w;
    float p2 = fmaf(2.f,d2,-q2.w) - c.w;
    float p3 = fmaf(2.f,d3,-q3.w) - c.w;
    unsigned long long keybase = (unsigned long long)(4095 - (j0 + lane));
    if (p0 >= T0) {
      int o = atomicAdd(&lcnt[w*4+0], 1);
      if (o < 128) lst[w*4+0][o] = ((unsigned long long)mono(p0) << 32) | keybase;
    }
    if (p1 >= T1) {
      int o = atomicAdd(&lcnt[w*4+1], 1);
      if (o < 128) lst[w*4+1][o] = ((unsigned long long)mono(p1) << 32) | keybase;
    }
    if (p2 >= T2) {
      int o = atomicAdd(&lcnt[w*4+2], 1);
      if (o < 128) lst[w*4+2][o] = ((unsigned long long)mono(p2) << 32) | keybase;
    }
    if (p3 >= T3) {
      int o = atomicAdd(&lcnt[w*4+3], 1);
      if (o < 128) lst[w*4+3][o] = ((unsigned long long)mono(p3) << 32) | keybase;
    }
  }

  // exact top-20 per query
  #pragma unroll 1
  for (int i = 0; i < 4; ++i) {
    const int li = w*4 + i;
    const int cn = lcnt[li];
    const int outbase = (b * NPTS + nb + i) * KNN;
    if (cn <= 64) {                       // common case: one sort
      unsigned long long v = (lane < cn) ? lst[li][lane] : 0ull;
      v = sort64_desc(v, lane);
      if (lane < KNN) idxb[outbase + lane] = 4095 - (int)(v & 0xFFFFFFFFull);
    } else if (cn <= 128) {               // rare: 20-round argmax on 2 regs
      unsigned long long e0 = lst[li][lane];
      unsigned long long e1 = (lane + 64 < cn) ? lst[li][lane + 64] : 0ull;
      #pragma unroll 1
      for (int r = 0; r < KNN; ++r) {
        unsigned long long m = e0 > e1 ? e0 : e1;
        #pragma unroll
        for (int o = 32; o; o >>= 1) {
          unsigned long long t = __shfl_xor(m, o);
          m = t > m ? t : m;
        }
        if (lane == 0) idxb[outbase + r] = 4095 - (int)(m & 0xFFFFFFFFull);
        if (e0 == m) e0 = 0ull; else if (e1 == m) e1 = 0ull;
      }
    } else {                              // ~never: exact full re-scan
      const float4 qq = (i == 0) ? q0 : (i == 1) ? q1 : (i == 2) ? q2 : q3;
      unsigned long long prev = ~0ull;
      #pragma unroll 1
      for (int r = 0; r < KNN; ++r) {
        unsigned long long best = 0ull;
        for (int j0 = 0; j0 < NPTS; j0 += 64) {
          float4 c = xb[j0 + lane];
          float dd = fmaf(qq.x,c.x, fmaf(qq.y,c.y, qq.z*c.z));
          float pd = fmaf(2.f,dd,-qq.w) - c.w;
          unsigned long long key = ((unsigned long long)mono(pd) << 32) |
                                   (unsigned long long)(4095 - (j0 + lane));
          if (key < prev && key > best) best = key;
        }
        #pragma unroll
        for (int o = 32; o; o >>= 1) {
          unsigned long long t = __shfl_xor(best, o);
          best = t > best ? t : best;
        }
        if (lane == 0) idxb[outbase + r] = 4095 - (int)(best & 0xFFFFFFFFull);
        prev = best;
      }
    }
  }
}

// ------------------------------- K2 moments --------------------------------
__global__ __launch_bounds__(256) void pf_mom(
    const float4* __restrict__ xp, const int* __restrict__ idxb,
    float* __restrict__ gm) {
  __shared__ float WM[4][27];
  const int tid = threadIdx.x, lane = tid & 63, w = tid >> 6;
  const int pt = blockIdx.x * 256 + tid;
  const float4 xi = xp[pt];
  const int ib = (pt >> 12) << 12;

  int idx[KNN];
  const int4* ip = (const int4*)(idxb + pt*KNN);
  #pragma unroll
  for (int q = 0; q < 5; ++q) {
    int4 v = ip[q];
    idx[q*4+0]=v.x; idx[q*4+1]=v.y; idx[q*4+2]=v.z; idx[q*4+3]=v.w;
  }
  float sj0=0,sj1=0,sj2=0, p0=0,p1=0,p2=0,p3=0,p4=0,p5=0;
  #pragma unroll
  for (int kk = 0; kk < KNN; ++kk) {
    float4 xj = xp[ib + idx[kk]];
    sj0 += xj.x; sj1 += xj.y; sj2 += xj.z;
    p0 = fmaf(xj.x,xj.x,p0); p1 = fmaf(xj.x,xj.y,p1); p2 = fmaf(xj.x,xj.z,p2);
    p3 = fmaf(xj.y,xj.y,p3); p4 = fmaf(xj.y,xj.z,p4); p5 = fmaf(xj.z,xj.z,p5);
  }
  float m[27];
  m[0]=sj0; m[1]=sj1; m[2]=sj2;
  m[3]=20.f*xi.x; m[4]=20.f*xi.y; m[5]=20.f*xi.z;
  m[6]=p0; m[7]=p1; m[8]=p2; m[9]=p3; m[10]=p4; m[11]=p5;
  m[12]=20.f*xi.x*xi.x; m[13]=20.f*xi.x*xi.y; m[14]=20.f*xi.x*xi.z;
  m[15]=20.f*xi.y*xi.y; m[16]=20.f*xi.y*xi.z; m[17]=20.f*xi.z*xi.z;
  m[18]=sj0*xi.x; m[19]=sj0*xi.y; m[20]=sj0*xi.z;
  m[21]=sj1*xi.x; m[22]=sj1*xi.y; m[23]=sj1*xi.z;
  m[24]=sj2*xi.x; m[25]=sj2*xi.y; m[26]=sj2*xi.z;
  #pragma unroll
  for (int c = 0; c < 27; ++c) {
    float v = m[c];
    #pragma unroll
    for (int o = 32; o; o >>= 1) v += __shfl_xor(v, o);
    m[c] = v;
  }
  if (lane == 0)
    #pragma unroll
    for (int c = 0; c < 27; ++c) WM[w][c] = m[c];
  __syncthreads();
  if (tid < 27) atomicAdd(&gm[tid], WM[0][tid]+WM[1][tid]+WM[2][tid]+WM[3][tid]);
}

// ------------------------------- K3 affine1 --------------------------------
__global__ void pf_affine1(const float* __restrict__ gm,
                           const float* __restrict__ W1,
                           const float* __restrict__ g1,
                           const float* __restrict__ be1,
                           unsigned short* __restrict__ w1s,
                           float* __restrict__ sh1e) {
  int c = threadIdx.x;
  if (c >= 64) return;
  const float* wr = W1 + c*6;
  const float wa[3] = {wr[0], wr[1], wr[2]};
  const float wb[3] = {wr[3], wr[4], wr[5]};
  const int si0[9] = {0,1,2, 1,3,4, 2,4,5};
  float syf = 0.f, sy2 = 0.f;
  #pragma unroll
  for (int a = 0; a < 3; ++a)
    syf += wa[a]*(gm[a] - gm[3+a]) + wb[a]*gm[3+a];
  #pragma unroll
  for (int a = 0; a < 3; ++a)
    #pragma unroll
    for (int bq = 0; bq < 3; ++bq) {
      int k = a*3 + bq, kt = bq*3 + a;
      float pjj = gm[6 + si0[k]], pii = gm[12 + si0[k]];
      float cc = gm[18 + k], ct = gm[18 + kt];
      float uu = pjj - cc - ct + pii;
      float uv = cc - pii;
      sy2 += wa[a]*wa[bq]*uu + 2.f*wa[a]*wb[bq]*uv + wb[a]*wb[bq]*pii;
    }
  const float inv = 1.0f / (float)CNT;
  float mean = syf * inv;
  float var  = sy2 * inv - mean * mean;
  float s  = g1[c] * rsqrtf(var + 1e-5f);
  sh1e[c]  = be1[c] - mean * s;
  unsigned short* o = w1s + c*8;
  o[0]=f2bf(s*wa[0]); o[1]=f2bf(s*wa[1]); o[2]=f2bf(s*wa[2]);
  o[3]=f2bf(s*wb[0]); o[4]=f2bf(s*wb[1]); o[5]=f2bf(s*wb[2]);
  o[6]=0; o[7]=0;
}

// ------------------------------- K4 stats2 ---------------------------------
// grid 512, 32 pts/block (two point-halves), 2-stage pipeline, 1 barrier/iter.
__global__ __launch_bounds__(256, 3) void pf_stats2(
    const float4* __restrict__ xp, const int* __restrict__ idxb,
    const unsigned short* __restrict__ w1s, const float* __restrict__ sh1e,
    const unsigned short* __restrict__ w2p,
    float* __restrict__ gs2, float* __restrict__ gq2) {
  __shared__ __align__(16) short8 AF[KNN][32];             // 10 KB
  __shared__ __align__(16) unsigned short H1[2][32][72];   // 9 KB
  __shared__ float SS[128], SQ[128];

  const int tid = threadIdx.x;
  const int lane = tid & 63, ww = tid >> 6;
  const int l15 = lane & 15, quad = lane >> 4;
  const int pt0 = blockIdx.x * 32;

  if (tid < 128) { SS[tid] = 0.f; SQ[tid] = 0.f; }

  for (int u = tid; u < 32*KNN; u += 256) {
    int kk = u >> 5, pp = u & 31;
    int pt = pt0 + pp;
    float4 xi = xp[pt];
    float4 xj = xp[((pt >> 12) << 12) + idxb[pt*KNN + kk]];
    PK8 U;
    U.u4[0] = cvtpk(xj.x-xi.x, xj.y-xi.y);
    U.u4[1] = cvtpk(xj.z-xi.z, xi.x);
    U.u4[2] = cvtpk(xi.y, xi.z);
    U.u4[3] = 0;
    AF[kk][pp] = U.s;
  }

  short8 w1f = *(const short8*)(w1s + (16*ww + l15)*8);
  floatx4 sh1v;
  #pragma unroll
  for (int r = 0; r < 4; ++r) sh1v[r] = sh1e[16*ww + 4*quad + r];

  short8 w2f[2][2];
  #pragma unroll
  for (int ks = 0; ks < 2; ++ks)
    #pragma unroll
    for (int t = 0; t < 2; ++t)
      w2f[ks][t] = *(const short8*)(w2p + (32*ww + 16*t + l15)*64 + 32*ks + quad*8);

  float sum[2][2][4] = {{{0,0,0,0},{0,0,0,0}},{{0,0,0,0},{0,0,0,0}}};
  float sq [2][2][4] = {{{0,0,0,0},{0,0,0,0}},{{0,0,0,0},{0,0,0,0}}};
  const short8 z8 = {0,0,0,0,0,0,0,0};
  __syncthreads();

  #pragma unroll 1
  for (int k = 0; k < KNN + 1; ++k) {
    // stage 2: L2(k-1) for both point-halves
    if (k >= 1) {
      #pragma unroll
      for (int ph = 0; ph < 2; ++ph) {
        floatx4 acc2[2] = {{0,0,0,0},{0,0,0,0}};
        #pragma unroll
        for (int ks = 0; ks < 2; ++ks) {
          short8 a = *(const short8*)&H1[(k-1) & 1][ph*16 + l15][ks*32 + quad*8];
          #pragma unroll
          for (int t = 0; t < 2; ++t)
            acc2[t] = __builtin_amdgcn_mfma_f32_16x16x32_bf16(w2f[ks][t], a, acc2[t], 0,0,0);
        }
        #pragma unroll
        for (int t = 0; t < 2; ++t)
          #pragma unroll
          for (int r = 0; r < 4; ++r) {
            float v = acc2[t][r];          // raw conv2 (bias cancels in BN)
            sum[ph][t][r] += v; sq[ph][t][r] = fmaf(v, v, sq[ph][t][r]);
          }
      }
    }
    // stage 1: L1(k) for both point-halves -> H1[k&1]
    if (k < KNN) {
      #pragma unroll
      for (int ph = 0; ph < 2; ++ph) {
        short8 a0 = z8;
        if (quad == 0) a0 = AF[k][ph*16 + l15];
        floatx4 c0 = sh1v;
        c0 = __builtin_amdgcn_mfma_f32_16x16x32_bf16(w1f, a0, c0, 0,0,0);
        store4bf_relu(&H1[k & 1][ph*16 + l15][16*ww + 4*quad], c0);
      }
    }
    __syncthreads();                       // single barrier per iteration
  }
  #pragma unroll
  for (int t = 0; t < 2; ++t)
    #pragma unroll
    for (int r = 0; r < 4; ++r) {
      float s = sum[0][t][r] + sum[1][t][r];
      float z = sq[0][t][r] + sq[1][t][r];
      s += __shfl_xor(s, 1); z += __shfl_xor(z, 1);
      s += __shfl_xor(s, 2); z += __shfl_xor(z, 2);
      s += __shfl_xor(s, 4); z += __shfl_xor(z, 4);
      s += __shfl_xor(s, 8); z += __shfl_xor(z, 8);
      if (l15 == 0) {
        int ch = 32*ww + 16*t + 4*quad + r;
        atomicAdd(&SS[ch], s); atomicAdd(&SQ[ch], z);
      }
    }
  __syncthreads();
  if (tid < 128) { atomicAdd(&gs2[tid], SS[tid]); atomicAdd(&gq2[tid], SQ[tid]); }
}

// ------------------------------- K5 main -----------------------------------
// grid 512, 32 pts/block (two point-halves), 3-stage pipeline, 1 barrier/iter.
// BN2 fold inlined (R6-proven pattern): cvtpk(s*W2) is RNE == f2bf(s*W2).
__global__ __launch_bounds__(256, 2) void pf_main(
    const float4* __restrict__ xp, const int* __restrict__ idxb,
    const unsigned short* __restrict__ w1s, const float* __restrict__ sh1e,
    const float* __restrict__ W2, const float* __restrict__ g2,
    const float* __restrict__ be2,
    const float* __restrict__ gs2, const float* __restrict__ gq2,
    const unsigned short* __restrict__ w3p,
    float* __restrict__ gs3, float* __restrict__ gq3,
    float* __restrict__ maxv) {
  __shared__ __align__(16) short8 AF[KNN][32];             // 10 KB
  __shared__ __align__(16) unsigned short H1[2][32][72];   // 9 KB
  __shared__ __align__(16) unsigned short H2[2][32][136];  // 17 KB
  __shared__ float SS[128], SQ[128];

  const int tid = threadIdx.x;
  const int lane = tid & 63, ww = tid >> 6;
  const int l15 = lane & 15, quad = lane >> 4;
  const int pt0 = blockIdx.x * 32;

  if (tid < 128) { SS[tid] = 0.f; SQ[tid] = 0.f; }

  for (int u = tid; u < 32*KNN; u += 256) {
    int kk = u >> 5, pp = u & 31;
    int pt = pt0 + pp;
    float4 xi = xp[pt];
    float4 xj = xp[((pt >> 12) << 12) + idxb[pt*KNN + kk]];
    PK8 U;
    U.u4[0] = cvtpk(xj.x-xi.x, xj.y-xi.y);
    U.u4[1] = cvtpk(xj.z-xi.z, xi.x);
    U.u4[2] = cvtpk(xi.y, xi.z);
    U.u4[3] = 0;
    AF[kk][pp] = U.s;
  }

  short8 w1f = *(const short8*)(w1s + (16*ww + l15)*8);
  floatx4 sh1v;
  #pragma unroll
  for (int r = 0; r < 4; ++r) sh1v[r] = sh1e[16*ww + 4*quad + r];

  // inline BN2 fold (scale-folded bf16 W2 fragments; simple bn_affine — safe)
  short8 w2f[2][2];
  #pragma unroll
  for (int t = 0; t < 2; ++t) {
    int row = 32*ww + 16*t + l15;
    float s_, sh_; bn_affine(gs2[row], gq2[row], g2[row], be2[row], s_, sh_);
    #pragma unroll
    for (int ks = 0; ks < 2; ++ks) {
      const float* pw = W2 + row*64 + 32*ks + quad*8;
      float4 wlo = *(const float4*)pw;
      float4 whi = *(const float4*)(pw + 4);
      PK8 U;
      U.u4[0] = cvtpk(s_*wlo.x, s_*wlo.y);
      U.u4[1] = cvtpk(s_*wlo.z, s_*wlo.w);
      U.u4[2] = cvtpk(s_*whi.x, s_*whi.y);
      U.u4[3] = cvtpk(s_*whi.z, s_*whi.w);
      w2f[ks][t] = U.s;
    }
  }
  floatx4 sh2v[2];
  #pragma unroll
  for (int t = 0; t < 2; ++t)
    #pragma unroll
    for (int r = 0; r < 4; ++r) {
      int ch = 32*ww + 16*t + 4*quad + r;
      float s_, sh_; bn_affine(gs2[ch], gq2[ch], g2[ch], be2[ch], s_, sh_);
      sh2v[t][r] = sh_;
    }
  short8 w3f[4][2];
  #pragma unroll
  for (int ks = 0; ks < 4; ++ks)
    #pragma unroll
    for (int t = 0; t < 2; ++t)
      w3f[ks][t] = *(const short8*)(w3p + (32*ww + 16*t + l15)*128 + 32*ks + quad*8);

  float sum[2][2][4] = {{{0,0,0,0},{0,0,0,0}},{{0,0,0,0},{0,0,0,0}}};
  float sq [2][2][4] = {{{0,0,0,0},{0,0,0,0}},{{0,0,0,0},{0,0,0,0}}};
  float mx [2][2][4];
  #pragma unroll
  for (int ph = 0; ph < 2; ++ph)
    #pragma unroll
    for (int t = 0; t < 2; ++t)
      #pragma unroll
      for (int r = 0; r < 4; ++r) mx[ph][t][r] = -3.0e38f;

  const short8 z8 = {0,0,0,0,0,0,0,0};
  __syncthreads();

  #pragma unroll 1
  for (int k = 0; k < KNN + 2; ++k) {
    // ---- stage 3: L3(k-2) from H2[(k-2)&1] == H2[k&1] ----
    if (k >= 2) {
      #pragma unroll
      for (int ph = 0; ph < 2; ++ph) {
        floatx4 acc3[2] = {{0,0,0,0},{0,0,0,0}};
        #pragma unroll
        for (int ks = 0; ks < 4; ++ks) {
          short8 a = *(const short8*)&H2[k & 1][ph*16 + l15][ks*32 + quad*8];
          #pragma unroll
          for (int t = 0; t < 2; ++t)
            acc3[t] = __builtin_amdgcn_mfma_f32_16x16x32_bf16(w3f[ks][t], a, acc3[t], 0,0,0);
        }
        #pragma unroll
        for (int t = 0; t < 2; ++t)
          #pragma unroll
          for (int r = 0; r < 4; ++r) {
            float v = acc3[t][r];
            sum[ph][t][r] += v; sq[ph][t][r] = fmaf(v, v, sq[ph][t][r]);
            mx[ph][t][r] = fmaxf(mx[ph][t][r], v);
          }
      }
    }
    // ---- stage 2: L2(k-1) from H1[(k-1)&1] -> H2[(k-1)&1] ----
    if (k >= 1 && k < KNN + 1) {
      #pragma unroll
      for (int ph = 0; ph < 2; ++ph) {
        floatx4 acc2[2] = {sh2v[0], sh2v[1]};
        #pragma unroll
        for (int ks = 0; ks < 2; ++ks) {
          short8 a = *(const short8*)&H1[(k-1) & 1][ph*16 + l15][ks*32 + quad*8];
          #pragma unroll
          for (int t = 0; t < 2; ++t)
            acc2[t] = __builtin_amdgcn_mfma_f32_16x16x32_bf16(w2f[ks][t], a, acc2[t], 0,0,0);
        }
        #pragma unroll
        for (int t = 0; t < 2; ++t)
          store4bf_relu(&H2[(k-1) & 1][ph*16 + l15][32*ww + 16*t + 4*quad], acc2[t]);
      }
    }
    // ---- stage 1: L1(k) -> H1[k&1] ----
    if (k < KNN) {
      #pragma unroll
      for (int ph = 0; ph < 2; ++ph) {
        short8 a0 = z8;
        if (quad == 0) a0 = AF[k][ph*16 + l15];
        floatx4 acc1 = sh1v;
        acc1 = __builtin_amdgcn_mfma_f32_16x16x32_bf16(w1f, a0, acc1, 0,0,0);
        store4bf_relu(&H1[k & 1][ph*16 + l15][16*ww + 4*quad], acc1);
      }
    }
    __syncthreads();                       // single barrier per iteration
  }

  #pragma unroll
  for (int ph = 0; ph < 2; ++ph)
    #pragma unroll
    for (int t = 0; t < 2; ++t) {
      int ch0 = 32*ww + 16*t + 4*quad;
      float4 o = make_float4(mx[ph][t][0], mx[ph][t][1], mx[ph][t][2], mx[ph][t][3]);
      *(float4*)&maxv[(size_t)(pt0 + ph*16 + l15)*128 + ch0] = o;
    }
  #pragma unroll
  for (int t = 0; t < 2; ++t)
    #pragma unroll
    for (int r = 0; r < 4; ++r) {
      float s = sum[0][t][r] + sum[1][t][r];
      float z = sq[0][t][r] + sq[1][t][r];
      s += __shfl_xor(s, 1); z += __shfl_xor(z, 1);
      s += __shfl_xor(s, 2); z += __shfl_xor(z, 2);
      s += __shfl_xor(s, 4); z += __shfl_xor(z, 4);
      s += __shfl_xor(s, 8); z += __shfl_xor(z, 8);
      if (l15 == 0) {
        int ch = 32*ww + 16*t + 4*quad + r;
        atomicAdd(&SS[ch], s); atomicAdd(&SQ[ch], z);
      }
    }
  __syncthreads();
  if (tid < 128) { atomicAdd(&gs3[tid], SS[tid]); atomicAdd(&gq3[tid], SQ[tid]); }
}

// ------------------------------- K6 output ---------------------------------
__global__ __launch_bounds__(256) void pf_out(
    const float* __restrict__ maxv,
    const float* __restrict__ gs3, const float* __restrict__ gq3,
    const float* __restrict__ g3, const float* __restrict__ be3,
    float* __restrict__ out) {
  __shared__ float T[128][17];
  __shared__ float SC[128], SH[128];
  const int tid = threadIdx.x;
  const int b  = blockIdx.x >> 8;
  const int n0 = (blockIdx.x & 255) * 16;
  if (tid < 128) {
    float s, sh; bn_affine(gs3[tid], gq3[tid], g3[tid], be3[tid], s, sh);
    SC[tid] = s; SH[tid] = sh;
  }
  __syncthreads();
  const float4* mv4 = (const float4*)maxv;
  #pragma unroll
  for (int r = 0; r < 2; ++r) {
    int fid = r * 256 + tid;
    int nl = fid >> 5, c4 = fid & 31;
    float4 v = mv4[(size_t)(b*NPTS + n0 + nl)*32 + c4];
    int c = c4 * 4;
    T[c+0][nl] = fmaf(SC[c+0], v.x, SH[c+0]);
    T[c+1][nl] = fmaf(SC[c+1], v.y, SH[c+1]);
    T[c+2][nl] = fmaf(SC[c+2], v.z, SH[c+2]);
    T[c+3][nl] = fmaf(SC[c+3], v.w, SH[c+3]);
  }
  __syncthreads();
  #pragma unroll
  for (int r = 0; r < 2; ++r) {
    int fid = r * 256 + tid;
    int c = fid >> 2, nq = fid & 3;
    float4 o;
    o.x = T[c][nq*4+0]; o.y = T[c][nq*4+1];
    o.z = T[c][nq*4+2]; o.w = T[c][nq*4+3];
    *(float4*)(out + (size_t)b*128*NPTS + (size_t)c*NPTS + n0 + nq*4) = o;
  }
}

// ------------------------------- launcher ----------------------------------
extern "C" void kernel_launch(void* const* d_in, const int* in_sizes, int n_in,
                              void* d_out, int out_size, void* d_ws, size_t ws_size,
                              hipStream_t stream) {
  const float* x   = (const float*)d_in[0];
  const float* W1  = (const float*)d_in[1];
  const float* g1  = (const float*)d_in[3];
  const float* be1 = (const float*)d_in[4];
  const float* W2  = (const float*)d_in[5];
  const float* g2  = (const float*)d_in[7];
  const float* be2 = (const float*)d_in[8];
  const float* W3  = (const float*)d_in[9];
  const float* g3  = (const float*)d_in[11];
  const float* be3 = (const float*)d_in[12];
  float* out = (float*)d_out;

  char* p = (char*)d_ws;
  float4* xp  = (float4*)p;            p += (size_t)BN_ * 16;
  int*    idxb= (int*)p;               p += (size_t)BN_ * KNN * 4;
  float*  stats = (float*)p;           p += 640 * 4;
  float*  aff   = (float*)p;           p += 256 * 4;               // sh1e
  unsigned short* w1s = (unsigned short*)p; p += 64 * 8 * 2;       // BN1-folded
  unsigned short* w2p = (unsigned short*)p; p += 128 * 64 * 2;     // raw bf16
  unsigned short* w3p = (unsigned short*)p; p += 128 * 128 * 2;    // raw bf16
  float*  maxv  = (float*)p;           // BN_*128*4 bytes

  float *gm  = stats;                  // 27 moment components
  float *gs2 = stats + 128, *gq2 = stats + 256;
  float *gs3 = stats + 384, *gq3 = stats + 512;
  float *sh1e = aff;

  pf_prep   <<<64,   256, 0, stream>>>(x, xp, stats, W2, W3, w2p, w3p);
  pf_knn    <<<1024, 256, 0, stream>>>(xp, idxb);
  pf_mom    <<<64,   256, 0, stream>>>(xp, idxb, gm);
  pf_affine1<<<1,    64,  0, stream>>>(gm, W1, g1, be1, w1s, sh1e);
  pf_stats2 <<<512,  256, 0, stream>>>(xp, idxb, w1s, sh1e, w2p, gs2, gq2);
  pf_main   <<<512,  256, 0, stream>>>(xp, idxb, w1s, sh1e, W2, g2, be2,
                                       gs2, gq2, w3p, gs3, gq3, maxv);
  pf_out    <<<1024, 256, 0, stream>>>(maxv, gs3, gq3, g3, be3, out);
}